// Round 2
// baseline (8347.768 us; speedup 1.0000x reference)
//
#include <hip/hip_runtime.h>
#include <hip/hip_bf16.h>

typedef __hip_bfloat16 bf16;

#define S_LEN 8192
#define HID   2048
#define QKV3  6144
#define NH    16
#define HD    128
#define NFW   4
#define FD    512
#define CHUNK_LEN 2048
#define NCHUNK 4
#define BASE_LR_INV (-6.9072552f)   // log(expm1(0.001))

__device__ __forceinline__ float bf2f(bf16 x){ return __bfloat162float(x); }
__device__ __forceinline__ bf16  f2bf(float x){ return __float2bfloat16(x); }
__device__ __forceinline__ float sigm(float x){ return 1.f/(1.f+__expf(-x)); }
__device__ __forceinline__ float siluf(float x){ return x/(1.f+__expf(-x)); }
__device__ __forceinline__ float wave_sum(float v){
  #pragma unroll
  for(int off=32; off; off>>=1) v += __shfl_xor(v, off, 64);
  return v;
}

__device__ __forceinline__ float ldf(const float* p){ return *p; }
__device__ __forceinline__ float ldf(const bf16* p){ return __bfloat162float(*p); }
__device__ __forceinline__ void  stf(float* p, float v){ *p = v; }
__device__ __forceinline__ void  stf(bf16*  p, float v){ *p = __float2bfloat16(v); }

// ---------------------------------------------------------------------------
// Generic fp32 tiled GEMM.
// C[M,N] (+)= op(A) * op(B);  a(m,k) = AT ? A[k*lda+m] : A[m*lda+k]
//                             b(k,n) = BT ? B[n*ldb+k] : B[k*ldb+n]
// blockDim 256, tile BM x BN, BK=16, thread tile TM x TN (BM=16*TM, BN=16*TN)
// batch via blockIdx.z with element strides sA/sB/sC. All dims must divide.
// ---------------------------------------------------------------------------
template<int BM,int BN,int TM,int TN,bool AT,bool BT,bool ACC,
         typename TA,typename TB,typename TC>
__global__ __launch_bounds__(256) void gemm_k(
    const TA* __restrict__ A, const TB* __restrict__ B, TC* __restrict__ C,
    int K, int lda, int ldb, int ldc, long sA, long sB, long sC)
{
  __shared__ __align__(16) float As[16][BM+4];
  __shared__ __align__(16) float Bs[16][BN+4];
  A += (size_t)blockIdx.z * sA;
  B += (size_t)blockIdx.z * sB;
  C += (size_t)blockIdx.z * sC;
  const int m0 = blockIdx.y * BM, n0 = blockIdx.x * BN;
  const int tid = threadIdx.x;
  const int ty = tid >> 4, tx = tid & 15;

  float acc[TM][TN];
  #pragma unroll
  for(int i=0;i<TM;i++)
    #pragma unroll
    for(int j=0;j<TN;j++) acc[i][j] = 0.f;

  for(int kt=0; kt<K; kt+=16){
    #pragma unroll
    for(int i=0;i<BM*16/256;i++){
      int e = tid + i*256;
      int m, kk;
      if(AT){ kk = e / BM; m = e % BM; }
      else  { m = e >> 4;  kk = e & 15; }
      float v = AT ? ldf(&A[(size_t)(kt+kk)*lda + (m0+m)])
                   : ldf(&A[(size_t)(m0+m)*lda + (kt+kk)]);
      As[kk][m] = v;
    }
    #pragma unroll
    for(int i=0;i<BN*16/256;i++){
      int e = tid + i*256;
      int n, kk;
      if(BT){ n = e >> 4;  kk = e & 15; }
      else  { kk = e / BN; n = e % BN; }
      float v = BT ? ldf(&B[(size_t)(n0+n)*ldb + (kt+kk)])
                   : ldf(&B[(size_t)(kt+kk)*ldb + (n0+n)]);
      Bs[kk][n] = v;
    }
    __syncthreads();
    #pragma unroll
    for(int kk=0;kk<16;kk++){
      float a[TM], b[TN];
      #pragma unroll
      for(int i=0;i<TM;i++) a[i] = As[kk][ty*TM+i];
      #pragma unroll
      for(int j=0;j<TN;j++) b[j] = Bs[kk][tx*TN+j];
      #pragma unroll
      for(int i=0;i<TM;i++)
        #pragma unroll
        for(int j=0;j<TN;j++) acc[i][j] += a[i]*b[j];
    }
    __syncthreads();
  }
  #pragma unroll
  for(int i=0;i<TM;i++){
    size_t row = (size_t)(m0 + ty*TM + i) * ldc;
    #pragma unroll
    for(int j=0;j<TN;j++){
      size_t idx = row + n0 + tx*TN + j;
      if constexpr (ACC) C[idx] += acc[i][j];
      else               stf(&C[idx], acc[i][j]);
    }
  }
}

template<int BM,int BN,int TM,int TN,bool AT,bool BT,bool ACC,
         typename TA,typename TB,typename TC>
static inline void gemm_go(hipStream_t st, const TA* A, const TB* B, TC* C,
    int M,int N,int K,int lda,int ldb,int ldc,int batch,long sA,long sB,long sC)
{
  dim3 grid(N/BN, M/BM, batch);
  gemm_k<BM,BN,TM,TN,AT,BT,ACC,TA,TB,TC><<<grid, 256, 0, st>>>(A,B,C,K,lda,ldb,ldc,sA,sB,sC);
}

// ---------------------------------------------------------------------------
// RoPE cos/sin tables: rc/rs[pos*64+d], d<64, theta=5e5
// ---------------------------------------------------------------------------
__global__ void rope_k(float* __restrict__ rc, float* __restrict__ rs){
  int pos = blockIdx.x, d = threadIdx.x;
  float inv = 1.f / powf(500000.0f, (float)d * (1.0f/64.0f));
  float ang = (float)pos * inv;
  rc[pos*64+d] = cosf(ang);
  rs[pos*64+d] = sinf(ang);
}

// ---------------------------------------------------------------------------
// per-token learning rates
// ---------------------------------------------------------------------------
__global__ __launch_bounds__(256) void lr_k(const float* __restrict__ hidden,
    const float* __restrict__ lr_w, const float* __restrict__ lr_b,
    float* __restrict__ lro)
{
  __shared__ float hrow[HID];
  __shared__ float red[4][12];
  int s = blockIdx.x, tid = threadIdx.x;
  for(int i=0;i<HID/256;i++) hrow[tid+256*i] = hidden[(size_t)s*HID + tid + 256*i];
  __syncthreads();
  float part[12];
  #pragma unroll
  for(int o=0;o<12;o++) part[o]=0.f;
  for(int i=0;i<HID/256;i++){
    int j = tid + 256*i;
    float h = hrow[j];
    #pragma unroll
    for(int o=0;o<12;o++) part[o] += h * lr_w[o*HID + j];
  }
  int lane = tid & 63, w = tid >> 6;
  #pragma unroll
  for(int o=0;o<12;o++){
    float v = wave_sum(part[o]);
    if(lane==0) red[w][o] = v;
  }
  __syncthreads();
  if(tid < 12){
    float v = red[0][tid]+red[1][tid]+red[2][tid]+red[3][tid] + lr_b[tid] + BASE_LR_INV;
    float sp = (v > 20.f) ? v : log1pf(expf(v));
    lro[s*12 + tid] = sp;
  }
}

// ---------------------------------------------------------------------------
// E2a: per-token rmsnorm(q), rmsnorm(k), in place in qkv (bf16).
// ---------------------------------------------------------------------------
__global__ __launch_bounds__(256) void e2a_k(
    bf16* __restrict__ qkv,
    const float* __restrict__ qnw, const float* __restrict__ knw)
{
  __shared__ float red[8];
  int s = blockIdx.x, tid = threadIdx.x;
  int lane = tid & 63, w = tid >> 6;
  float qv[8], kv[8];
  float sq = 0.f, sk = 0.f;
  size_t base = (size_t)s*QKV3;
  #pragma unroll
  for(int i=0;i<8;i++){
    int j = tid*8 + i;
    qv[i] = bf2f(qkv[base + j]);
    kv[i] = bf2f(qkv[base + HID + j]);
    sq += qv[i]*qv[i]; sk += kv[i]*kv[i];
  }
  sq = wave_sum(sq); sk = wave_sum(sk);
  if(lane==0){ red[w] = sq; red[4+w] = sk; }
  __syncthreads();
  float rq = rsqrtf((red[0]+red[1]+red[2]+red[3])*(1.f/HID) + 1e-6f);
  float rk = rsqrtf((red[4]+red[5]+red[6]+red[7])*(1.f/HID) + 1e-6f);
  #pragma unroll
  for(int i=0;i<8;i++){
    int j = tid*8 + i;
    qkv[base + j]       = f2bf(qv[i]*rq*qnw[j]);
    qkv[base + HID + j] = f2bf(kv[i]*rk*knw[j]);
  }
}

// ---------------------------------------------------------------------------
// E2b (after attention): overwrite q/k/v regions with fq/fk/fv.
// fq = l2norm_512(silu(qn*s0+o0)), fk = l2norm_512(silu(kn*s1+o1)), fv=silu(v)
// wave w handles fast-head w (elements j = w*512 + lane*8 + i = tid*8+i).
// ---------------------------------------------------------------------------
__global__ __launch_bounds__(256) void e2b_k(
    bf16* __restrict__ qkv,
    const float* __restrict__ qks, const float* __restrict__ qko)
{
  int s = blockIdx.x, tid = threadIdx.x;
  size_t base = (size_t)s*QKV3;
  float a[8], b[8], vv[8];
  float ga = 0.f, gb = 0.f;
  #pragma unroll
  for(int i=0;i<8;i++){
    int j = tid*8 + i;
    float qn = bf2f(qkv[base + j]);
    float kn = bf2f(qkv[base + HID + j]);
    float v  = bf2f(qkv[base + 2*HID + j]);
    a[i] = siluf(qn*qks[2*j]   + qko[2*j]);
    b[i] = siluf(kn*qks[2*j+1] + qko[2*j+1]);
    vv[i] = siluf(v);
    ga += a[i]*a[i]; gb += b[i]*b[i];
  }
  ga = wave_sum(ga); gb = wave_sum(gb);
  float iq = 1.f / fmaxf(sqrtf(ga), 1e-12f);
  float ik = 1.f / fmaxf(sqrtf(gb), 1e-12f);
  #pragma unroll
  for(int i=0;i<8;i++){
    int j = tid*8 + i;
    qkv[base + j]         = f2bf(a[i]*iq);
    qkv[base + HID + j]   = f2bf(b[i]*ik);
    qkv[base + 2*HID + j] = f2bf(vv[i]);
  }
}

// ---------------------------------------------------------------------------
// Sliding-window attention (window 256 incl self), flash-style over 5 key
// tiles of 64. One block = 1 head x 64 queries. Output fp32 into attn (d_out).
// ---------------------------------------------------------------------------
__global__ __launch_bounds__(256) void attn_k(
    const bf16* __restrict__ qkv,
    const float* __restrict__ rc, const float* __restrict__ rs,
    float* __restrict__ attn)
{
  __shared__ __align__(16) bf16  Qs[64][132];
  __shared__ __align__(16) float KVs[64][132];
  const int head = blockIdx.x >> 7;
  const int Q0 = (blockIdx.x & 127) * 64;
  const int tid = threadIdx.x;
  const int hb = head * HD;

  #pragma unroll
  for(int i=0;i<16;i++){
    int e = tid + i*256;
    int rr = e >> 6, d = e & 63;
    int qpos = Q0 + rr;
    size_t b = (size_t)qpos*QKV3 + hb;
    float x1 = bf2f(qkv[b + d]);
    float x2 = bf2f(qkv[b + d + 64]);
    float c = rc[qpos*64 + d], sn = rs[qpos*64 + d];
    Qs[rr][d]      = f2bf(x1*c - x2*sn);
    Qs[rr][d + 64] = f2bf(x2*c + x1*sn);
  }

  const int r = tid >> 2, sub = tid & 3;
  const int qpos = Q0 + r;
  const int lanebase = (tid & 63) & ~3;
  float m = -INFINITY, l = 0.f;
  float O[32];
  #pragma unroll
  for(int q=0;q<32;q++) O[q] = 0.f;

  for(int kt=0; kt<5; kt++){
    const int kb = Q0 - 256 + kt*64;
    __syncthreads();
    #pragma unroll
    for(int i=0;i<16;i++){
      int e = tid + i*256;
      int rr = e >> 6, d = e & 63;
      int kpos = kb + rr;
      float o1 = 0.f, o2 = 0.f;
      if(kpos >= 0){
        size_t b = (size_t)kpos*QKV3 + HID + hb;
        float x1 = bf2f(qkv[b + d]);
        float x2 = bf2f(qkv[b + d + 64]);
        float c = rc[kpos*64 + d], sn = rs[kpos*64 + d];
        o1 = x1*c - x2*sn; o2 = x2*c + x1*sn;
      }
      KVs[rr][d] = o1; KVs[rr][d+64] = o2;
    }
    __syncthreads();

    float sc[16];
    #pragma unroll
    for(int i=0;i<16;i++) sc[i] = 0.f;
    for(int dq=0; dq<32; dq++){
      float q0 = bf2f(Qs[r][4*dq+0]);
      float q1 = bf2f(Qs[r][4*dq+1]);
      float q2 = bf2f(Qs[r][4*dq+2]);
      float q3 = bf2f(Qs[r][4*dq+3]);
      #pragma unroll
      for(int i=0;i<16;i++){
        const float* kr = &KVs[4*i+sub][4*dq];
        sc[i] += q0*kr[0] + q1*kr[1] + q2*kr[2] + q3*kr[3];
      }
    }
    unsigned vmask = 0;
    #pragma unroll
    for(int i=0;i<16;i++){
      int kpos = kb + 4*i + sub;
      bool valid = (kpos >= 0) && (kpos > qpos - 256) && (kpos <= qpos);
      sc[i] = valid ? sc[i]*0.088388347648318447f : -INFINITY;
      vmask |= valid ? (1u<<i) : 0u;
    }
    float tmax = -INFINITY;
    #pragma unroll
    for(int i=0;i<16;i++) tmax = fmaxf(tmax, sc[i]);
    tmax = fmaxf(tmax, __shfl_xor(tmax, 1, 64));
    tmax = fmaxf(tmax, __shfl_xor(tmax, 2, 64));
    float mnew = fmaxf(m, tmax);
    float alpha = (mnew == m) ? 1.f : __expf(m - mnew);
    float p[16];
    float psum = 0.f;
    #pragma unroll
    for(int i=0;i<16;i++){
      float pv = ((vmask >> i) & 1u) ? __expf(sc[i] - mnew) : 0.f;
      p[i] = pv; psum += pv;
    }
    psum += __shfl_xor(psum, 1, 64);
    psum += __shfl_xor(psum, 2, 64);
    l = l*alpha + psum;
    m = mnew;
    #pragma unroll
    for(int q=0;q<32;q++) O[q] *= alpha;

    __syncthreads();
    #pragma unroll
    for(int i=0;i<32;i++){
      int e = tid + i*256;
      int rr = e >> 7, d = e & 127;
      int kpos = kb + rr;
      KVs[rr][d] = (kpos >= 0) ? bf2f(qkv[(size_t)kpos*QKV3 + 2*HID + hb + d]) : 0.f;
    }
    __syncthreads();
    #pragma unroll
    for(int j=0;j<64;j++){
      float pj = __shfl(p[j>>2], lanebase + (j&3), 64);
      const float* vr = &KVs[j][sub*32];
      #pragma unroll
      for(int q=0;q<32;q++) O[q] += pj * vr[q];
    }
  }
  float invl = 1.f / l;
  size_t ob = (size_t)qpos*HID + hb + sub*32;
  #pragma unroll
  for(int q=0;q<32;q++) attn[ob + q] = O[q] * invl;
}

// ---------------------------------------------------------------------------
// TTT elementwise fwd: hid = silu(g)*hm ; opre = silu(qg)*qm (opre -> qg buf)
// ---------------------------------------------------------------------------
__global__ __launch_bounds__(256) void e3_k(
    const bf16* __restrict__ g, const bf16* __restrict__ hm,
    bf16* __restrict__ qg, const bf16* __restrict__ qm,
    bf16* __restrict__ hid)
{
  size_t idx = (size_t)blockIdx.x*256 + threadIdx.x;
  float opre = siluf(bf2f(qg[idx])) * bf2f(qm[idx]);
  hid[idx] = f2bf(siluf(bf2f(g[idx])) * bf2f(hm[idx]));
  qg[idx]  = f2bf(opre);
}

// ---------------------------------------------------------------------------
// TTT backprop elementwise (in place): a0->g, a2->hm, a1->dhid buffer.
// fv read from the qkv v-region.
// ---------------------------------------------------------------------------
__global__ __launch_bounds__(256) void e4_k(
    bf16* __restrict__ g, bf16* __restrict__ hm, bf16* __restrict__ dhid,
    const bf16* __restrict__ qkv, const float* __restrict__ lrb, int cbase)
{
  size_t idx = (size_t)blockIdx.x*256 + threadIdx.x;
  int h  = (int)(idx >> 20);          // CHUNK_LEN*FD = 2^20
  int ci = (int)((idx >> 9) & 2047);
  int d  = (int)(idx & 511);
  int s  = cbase + ci;
  float l0  = lrb[s*12 + h];
  float l1  = lrb[s*12 + 4 + h];
  float l2v = lrb[s*12 + 8 + h];
  float gg = bf2f(g[idx]), hv = bf2f(hm[idx]), dh = bf2f(dhid[idx]);
  float sg = sigm(gg);
  float silu_g = gg * sg;
  float dhm = dh * silu_g;
  float dg  = dh * hv;
  float dgp = dg * (sg * (1.f + gg * (1.f - sg)));
  float fvv = bf2f(qkv[(size_t)s*QKV3 + 2*HID + h*FD + d]);
  g[idx]    = f2bf(dgp * l0);
  hm[idx]   = f2bf(dhm * l2v);
  dhid[idx] = f2bf(fvv * l1);
}

// ---------------------------------------------------------------------------
// E5 (per chunk): X = attn + rmsnorm(ofc)*ttt_norm_w -> q region of qkv (bf16)
// ---------------------------------------------------------------------------
__global__ __launch_bounds__(256) void e5_k(const float* __restrict__ attn,
    const bf16* __restrict__ ofc, const float* __restrict__ tnw,
    bf16* __restrict__ qkv, int cbase)
{
  int ci = blockIdx.x, tid = threadIdx.x;
  int s = cbase + ci;
  int lane = tid & 63, w = tid >> 6;
  float o[8]; float ss = 0.f;
  size_t ob = ((size_t)w*CHUNK_LEN + ci)*FD + (size_t)lane*8;
  #pragma unroll
  for(int i=0;i<8;i++){ o[i] = bf2f(ofc[ob+i]); ss += o[i]*o[i]; }
  ss = wave_sum(ss);
  float inv = rsqrtf(ss*(1.f/FD) + 1e-6f);
  size_t xb = (size_t)s*QKV3 + w*FD + (size_t)lane*8;
  size_t ab = (size_t)s*HID  + w*FD + (size_t)lane*8;
  #pragma unroll
  for(int i=0;i<8;i++){
    int d = lane*8 + i;
    qkv[xb+i] = f2bf(attn[ab+i] + o[i]*inv*tnw[d]);
  }
}

// ---------------------------------------------------------------------------
extern "C" void kernel_launch(void* const* d_in, const int* in_sizes, int n_in,
                              void* d_out, int out_size, void* d_ws, size_t ws_size,
                              hipStream_t stream)
{
  (void)in_sizes; (void)n_in; (void)out_size;
  const float* hidden   = (const float*)d_in[0];
  const float* qkv_w    = (const float*)d_in[1];
  const float* q_norm_w = (const float*)d_in[2];
  const float* k_norm_w = (const float*)d_in[3];
  const float* qk_scale = (const float*)d_in[4];
  const float* qk_off   = (const float*)d_in[5];
  const float* lr_w     = (const float*)d_in[6];
  const float* lr_b     = (const float*)d_in[7];
  const float* w0_in    = (const float*)d_in[8];
  const float* w1_in    = (const float*)d_in[9];
  const float* w2_in    = (const float*)d_in[10];
  const float* ttt_nw   = (const float*)d_in[11];
  const float* o_proj   = (const float*)d_in[12];
  float* out = (float*)d_out;

  char* p = (char*)d_ws;
  auto alloc = [&](size_t n){ char* r = p; p += (n + 255) & ~(size_t)255; return (void*)r; };

  bf16*  qkv   = (bf16*) alloc((size_t)S_LEN*QKV3*sizeof(bf16));  // raw qkv -> qn/kn/v -> fq/fk/fv -> X in q region
  float* lrb   = (float*)alloc((size_t)S_LEN*12*sizeof(float));
  float* rc    = (float*)alloc((size_t)S_LEN*64*sizeof(float));
  float* rs    = (float*)alloc((size_t)S_LEN*64*sizeof(float));
  float* w0s   = (float*)alloc((size_t)NFW*FD*FD*sizeof(float));
  float* w1s   = (float*)alloc((size_t)NFW*FD*FD*sizeof(float));
  float* w2s   = (float*)alloc((size_t)NFW*FD*FD*sizeof(float));
  bf16*  gb    = (bf16*) alloc((size_t)NFW*CHUNK_LEN*FD*sizeof(bf16));  // g -> a0
  bf16*  hmb   = (bf16*) alloc((size_t)NFW*CHUNK_LEN*FD*sizeof(bf16));  // hm -> a2
  bf16*  qgb   = (bf16*) alloc((size_t)NFW*CHUNK_LEN*FD*sizeof(bf16));  // qg -> opre
  bf16*  qmb   = (bf16*) alloc((size_t)NFW*CHUNK_LEN*FD*sizeof(bf16));  // qm -> dhid -> a1
  bf16*  hidb  = (bf16*) alloc((size_t)NFW*CHUNK_LEN*FD*sizeof(bf16));  // hid
  bf16*  ofc   = (bf16*) alloc((size_t)NFW*CHUNK_LEN*FD*sizeof(bf16));  // ofast chunk

  // workspace guard: fail cleanly (absmax) instead of faulting if too small
  if ((size_t)(p - (char*)d_ws) > ws_size) return;

  // attn lives in d_out until the final projection overwrites it
  float* attn = out;

  hipMemcpyAsync(w0s, w0_in, (size_t)NFW*FD*FD*sizeof(float), hipMemcpyDeviceToDevice, stream);
  hipMemcpyAsync(w1s, w1_in, (size_t)NFW*FD*FD*sizeof(float), hipMemcpyDeviceToDevice, stream);
  hipMemcpyAsync(w2s, w2_in, (size_t)NFW*FD*FD*sizeof(float), hipMemcpyDeviceToDevice, stream);

  rope_k<<<S_LEN, 64, 0, stream>>>(rc, rs);
  lr_k<<<S_LEN, 256, 0, stream>>>(hidden, lr_w, lr_b, lrb);

  // qkv = hidden @ qkv_w^T -> bf16
  gemm_go<128,128,8,8,false,true,false>(stream, hidden, qkv_w, qkv,
      S_LEN, QKV3, HID, HID, HID, QKV3, 1, 0,0,0);

  e2a_k<<<S_LEN, 256, 0, stream>>>(qkv, q_norm_w, k_norm_w);
  attn_k<<<NH*128, 256, 0, stream>>>(qkv, rc, rs, attn);
  e2b_k<<<S_LEN, 256, 0, stream>>>(qkv, qk_scale, qk_off);

  const long sW  = (long)FD*FD;          // head stride in fast weights
  const long sCh = (long)CHUNK_LEN*FD;   // head stride in chunk buffers
  const int  NEL = NFW*CHUNK_LEN*FD/256;

  for(int c=0; c<NCHUNK; c++){
    const bf16* fqc = qkv + (size_t)c*CHUNK_LEN*QKV3;
    const bf16* fkc = fqc + HID;
    const bf16* fvc = fqc + 2*HID;
    // forward matmuls against current weights (A strided in qkv, head stride FD)
    gemm_go<64,64,4,4,false,true,false>(stream, fkc, w0s, gb,  CHUNK_LEN, FD, FD, QKV3, FD, FD, NFW, FD, sW, sCh);
    gemm_go<64,64,4,4,false,true,false>(stream, fkc, w2s, hmb, CHUNK_LEN, FD, FD, QKV3, FD, FD, NFW, FD, sW, sCh);
    gemm_go<64,64,4,4,false,true,false>(stream, fqc, w0s, qgb, CHUNK_LEN, FD, FD, QKV3, FD, FD, NFW, FD, sW, sCh);
    gemm_go<64,64,4,4,false,true,false>(stream, fqc, w2s, qmb, CHUNK_LEN, FD, FD, QKV3, FD, FD, NFW, FD, sW, sCh);
    e3_k<<<NEL, 256, 0, stream>>>(gb, hmb, qgb, qmb, hidb);
    // o = opre @ w1^T -> ofc ; dhid = fv @ w1 -> qmb
    gemm_go<64,64,4,4,false,true,false>(stream, qgb, w1s, ofc, CHUNK_LEN, FD, FD, FD, FD, FD, NFW, sCh, sW, sCh);
    gemm_go<64,64,4,4,false,false,false>(stream, fvc, w1s, qmb, CHUNK_LEN, FD, FD, QKV3, FD, FD, NFW, FD, sW, sCh);
    e4_k<<<NEL, 256, 0, stream>>>(gb, hmb, qmb, qkv, lrb, c*CHUNK_LEN);
    // weight updates: w += a^T @ b   (M=N=512, K=2048)
    gemm_go<64,64,4,4,true,false,true>(stream, gb,  fkc,  w0s, FD, FD, CHUNK_LEN, FD, QKV3, FD, NFW, sCh, FD, sW);
    gemm_go<64,64,4,4,true,false,true>(stream, hmb, fkc,  w2s, FD, FD, CHUNK_LEN, FD, QKV3, FD, NFW, sCh, FD, sW);
    gemm_go<64,64,4,4,true,false,true>(stream, qmb, hidb, w1s, FD, FD, CHUNK_LEN, FD, FD,   FD, NFW, sCh, sCh, sW);
    // fold this chunk's output into X (q region of qkv) — fq of this chunk is dead now
    e5_k<<<CHUNK_LEN, 256, 0, stream>>>(attn, ofc, ttt_nw, qkv, c*CHUNK_LEN);
  }

  // out = X @ o_proj^T  (X = bf16 in q region of qkv, row stride QKV3)
  gemm_go<128,128,8,8,false,true,false>(stream, qkv, o_proj, out,
      S_LEN, HID, HID, QKV3, HID, HID, 1, 0,0,0);
}

// Round 3
// 3150.917 us; speedup vs baseline: 2.6493x; 2.6493x over previous
//
#include <hip/hip_runtime.h>
#include <hip/hip_bf16.h>

typedef __hip_bfloat16 bf16;
typedef __bf16 bft;
typedef bft bf16x8 __attribute__((ext_vector_type(8)));
typedef bft bf16x4 __attribute__((ext_vector_type(4)));
typedef float f32x4 __attribute__((ext_vector_type(4)));

#define S_LEN 8192
#define HID   2048
#define QKV3  6144
#define NH    16
#define HD    128
#define NFW   4
#define FD    512
#define CHUNK_LEN 2048
#define NCHUNK 4
#define BASE_LR_INV (-6.9072552f)   // log(expm1(0.001))
#define BKP 40                      // LDS K-stride (32 + 8 pad), 80B rows (16B aligned)

__device__ __forceinline__ float bf2f(bf16 x){ return __bfloat162float(x); }
__device__ __forceinline__ bf16  f2bf(float x){ return __float2bfloat16(x); }
__device__ __forceinline__ float sigm(float x){ return 1.f/(1.f+__expf(-x)); }
__device__ __forceinline__ float siluf(float x){ return x/(1.f+__expf(-x)); }
__device__ __forceinline__ float wave_sum(float v){
  #pragma unroll
  for(int off=32; off; off>>=1) v += __shfl_xor(v, off, 64);
  return v;
}

// ---------------------------------------------------------------------------
// LDS tile staging: ROWS x 32 k-slice, bf16 (direct) or fp32 (convert) source.
// dst is [ROWS][BKP] bf16.
// ---------------------------------------------------------------------------
template<int ROWS, typename T>
__device__ __forceinline__ void stage_tile(const T* __restrict__ src, long ld,
                                           bft* dst, int tid)
{
  if constexpr (sizeof(T) == 2) {
    #pragma unroll
    for (int i = 0; i < ROWS/64; ++i) {
      int e = tid + i*256;
      int m = e >> 2, k8 = (e & 3) * 8;
      bf16x8 v = *(const bf16x8*)(src + (size_t)m*ld + k8);
      *(bf16x8*)(dst + (size_t)m*BKP + k8) = v;
    }
  } else {
    #pragma unroll
    for (int i = 0; i < ROWS/32; ++i) {
      int e = tid + i*256;
      int m = e >> 3, k4 = (e & 7) * 4;
      const float4 v = *(const float4*)(src + (size_t)m*ld + k4);
      bf16x4 b; b[0]=(bft)v.x; b[1]=(bft)v.y; b[2]=(bft)v.z; b[3]=(bft)v.w;
      *(bf16x4*)(dst + (size_t)m*BKP + k4) = b;
    }
  }
}

// ---------------------------------------------------------------------------
// MFMA NT GEMM: C[M,N] (+)= A[M,K] * B[N,K]^T, fp32 accumulate.
// A/B: bf16 or fp32 (converted during staging). 256 threads, 4 waves in 2x2,
// each wave (BM/2)x(BN/2) via (BM/32)x(BN/32) grid of 16x16x32 MFMAs.
// EPI: 0 = store bf16, 1 = store fp32, 2 = fp32 C += acc (+ optional
// transposed bf16 shadow Ct[n*512+m], for w1^T maintenance).
// Batched over blockIdx.z with element strides sA/sB/sC. All dims divide.
// ---------------------------------------------------------------------------
template<int BM,int BN,int EPI, typename TA, typename TB>
__global__ __launch_bounds__(256) void mgemm_k(
    const TA* __restrict__ A, const TB* __restrict__ B, void* __restrict__ Cv,
    bft* __restrict__ Ct, int K, long lda, long ldb, long ldc,
    long sA, long sB, long sC)
{
  constexpr int AM = BM/32, AN = BN/32;
  __shared__ __align__(16) bft As[BM*BKP];
  __shared__ __align__(16) bft Bs[BN*BKP];
  const int tid = threadIdx.x;
  const int z = blockIdx.z;
  A += (size_t)z * sA;
  B += (size_t)z * sB;
  const size_t m0 = (size_t)blockIdx.y * BM, n0 = (size_t)blockIdx.x * BN;
  const int wv = tid >> 6, lane = tid & 63;
  const int wm = (wv & 1) * (BM/2), wn = (wv >> 1) * (BN/2);
  const int fr = lane & 15, fko = (lane >> 4) * 8;

  f32x4 acc[AM][AN];
  #pragma unroll
  for (int i=0;i<AM;i++)
    #pragma unroll
    for (int j=0;j<AN;j++) acc[i][j] = (f32x4){0.f,0.f,0.f,0.f};

  const TA* Ab = A + m0*lda;
  const TB* Bb = B + n0*ldb;
  for (int kt = 0; kt < K; kt += 32) {
    __syncthreads();
    stage_tile<BM>(Ab + kt, lda, As, tid);
    stage_tile<BN>(Bb + kt, ldb, Bs, tid);
    __syncthreads();
    bf16x8 af[AM], bfv[AN];
    #pragma unroll
    for (int mi=0; mi<AM; mi++)
      af[mi] = *(const bf16x8*)(As + (size_t)(wm + mi*16 + fr)*BKP + fko);
    #pragma unroll
    for (int ni=0; ni<AN; ni++)
      bfv[ni] = *(const bf16x8*)(Bs + (size_t)(wn + ni*16 + fr)*BKP + fko);
    #pragma unroll
    for (int mi=0; mi<AM; mi++)
      #pragma unroll
      for (int ni=0; ni<AN; ni++)
        acc[mi][ni] = __builtin_amdgcn_mfma_f32_16x16x32_bf16(af[mi], bfv[ni], acc[mi][ni], 0, 0, 0);
  }

  const int er = (lane >> 4) * 4;   // C/D: row=(lane>>4)*4+reg, col=lane&15
  const int ec = lane & 15;
  #pragma unroll
  for (int mi=0; mi<AM; mi++){
    #pragma unroll
    for (int ni=0; ni<AN; ni++){
      #pragma unroll
      for (int r=0; r<4; r++){
        size_t row = m0 + wm + mi*16 + er + r;
        size_t col = n0 + wn + ni*16 + ec;
        size_t idx = (size_t)z*sC + row*ldc + col;
        float v = acc[mi][ni][r];
        if constexpr (EPI == 0){
          ((bft*)Cv)[idx] = (bft)v;
        } else if constexpr (EPI == 1){
          ((float*)Cv)[idx] = v;
        } else {
          float nv = ((float*)Cv)[idx] + v;
          ((float*)Cv)[idx] = nv;
          if (Ct) Ct[(size_t)z*FD*FD + col*FD + row] = (bft)nv;
        }
      }
    }
  }
}

template<int BM,int BN,int EPI, typename TA, typename TB>
static inline void mgemm(hipStream_t st, const TA* A, const TB* B, void* C, bft* Ct,
    int M, int N, int K, long lda, long ldb, long ldc,
    int batch, long sA, long sB, long sC)
{
  dim3 g(N/BN, M/BM, batch);
  mgemm_k<BM,BN,EPI,TA,TB><<<g, 256, 0, st>>>(A, B, C, Ct, K, lda, ldb, ldc, sA, sB, sC);
}

// ---------------------------------------------------------------------------
// Batched bf16 transpose: out[z][c][r] = in[z][r][c], R=2048 rows, C=512 cols,
// ldout = 2048. 64x64 LDS tiles. grid (C/64, R/64, batch).
// ---------------------------------------------------------------------------
__global__ __launch_bounds__(256) void tr_k(const bft* __restrict__ in,
    bft* __restrict__ out, long ldin, long sIn, long sOut)
{
  __shared__ __align__(16) bft t[64][72];
  const int c0 = blockIdx.x*64, r0 = blockIdx.y*64;
  in  += (size_t)blockIdx.z * sIn;
  out += (size_t)blockIdx.z * sOut;
  const int tid = threadIdx.x;
  #pragma unroll
  for (int i=0;i<2;i++){
    int e = tid + i*256;
    int r = e >> 3, c8 = (e & 7) * 8;
    *(bf16x8*)&t[r][c8] = *(const bf16x8*)(in + (size_t)(r0+r)*ldin + c0 + c8);
  }
  __syncthreads();
  #pragma unroll
  for (int i=0;i<2;i++){
    int e = tid + i*256;
    int c = e >> 3, r8 = (e & 7) * 8;
    bf16x8 v;
    #pragma unroll
    for (int j=0;j<8;j++) v[j] = t[r8+j][c];
    *(bf16x8*)(out + (size_t)(c0+c)*CHUNK_LEN + r0 + r8) = v;
  }
}

// initial w1^T bf16 shadow: w1tb[z][h][o] = (bf16)w1[z][o][h]
__global__ __launch_bounds__(256) void tcw1_k(const float* __restrict__ w1,
    bft* __restrict__ w1tb)
{
  size_t idx = (size_t)blockIdx.x*256 + threadIdx.x;   // z*262144 + h*512 + o
  int z = (int)(idx >> 18);
  int h = (int)((idx >> 9) & 511);
  int o = (int)(idx & 511);
  w1tb[idx] = (bft)w1[(size_t)z*FD*FD + (size_t)o*FD + h];
}

// ---------------------------------------------------------------------------
// RoPE cos/sin tables: rc/rs[pos*64+d], d<64, theta=5e5
// ---------------------------------------------------------------------------
__global__ void rope_k(float* __restrict__ rc, float* __restrict__ rs){
  int pos = blockIdx.x, d = threadIdx.x;
  float inv = 1.f / powf(500000.0f, (float)d * (1.0f/64.0f));
  float ang = (float)pos * inv;
  rc[pos*64+d] = cosf(ang);
  rs[pos*64+d] = sinf(ang);
}

// ---------------------------------------------------------------------------
// per-token learning rates
// ---------------------------------------------------------------------------
__global__ __launch_bounds__(256) void lr_k(const float* __restrict__ hidden,
    const float* __restrict__ lr_w, const float* __restrict__ lr_b,
    float* __restrict__ lro)
{
  __shared__ float hrow[HID];
  __shared__ float red[4][12];
  int s = blockIdx.x, tid = threadIdx.x;
  for(int i=0;i<HID/256;i++) hrow[tid+256*i] = hidden[(size_t)s*HID + tid + 256*i];
  __syncthreads();
  float part[12];
  #pragma unroll
  for(int o=0;o<12;o++) part[o]=0.f;
  for(int i=0;i<HID/256;i++){
    int j = tid + 256*i;
    float h = hrow[j];
    #pragma unroll
    for(int o=0;o<12;o++) part[o] += h * lr_w[o*HID + j];
  }
  int lane = tid & 63, w = tid >> 6;
  #pragma unroll
  for(int o=0;o<12;o++){
    float v = wave_sum(part[o]);
    if(lane==0) red[w][o] = v;
  }
  __syncthreads();
  if(tid < 12){
    float v = red[0][tid]+red[1][tid]+red[2][tid]+red[3][tid] + lr_b[tid] + BASE_LR_INV;
    float sp = (v > 20.f) ? v : log1pf(expf(v));
    lro[s*12 + tid] = sp;
  }
}

// ---------------------------------------------------------------------------
// E2a: per-token rmsnorm(q), rmsnorm(k), in place in qkv (bf16).
// ---------------------------------------------------------------------------
__global__ __launch_bounds__(256) void e2a_k(
    bf16* __restrict__ qkv,
    const float* __restrict__ qnw, const float* __restrict__ knw)
{
  __shared__ float red[8];
  int s = blockIdx.x, tid = threadIdx.x;
  int lane = tid & 63, w = tid >> 6;
  float qv[8], kv[8];
  float sq = 0.f, sk = 0.f;
  size_t base = (size_t)s*QKV3;
  #pragma unroll
  for(int i=0;i<8;i++){
    int j = tid*8 + i;
    qv[i] = bf2f(qkv[base + j]);
    kv[i] = bf2f(qkv[base + HID + j]);
    sq += qv[i]*qv[i]; sk += kv[i]*kv[i];
  }
  sq = wave_sum(sq); sk = wave_sum(sk);
  if(lane==0){ red[w] = sq; red[4+w] = sk; }
  __syncthreads();
  float rq = rsqrtf((red[0]+red[1]+red[2]+red[3])*(1.f/HID) + 1e-6f);
  float rk = rsqrtf((red[4]+red[5]+red[6]+red[7])*(1.f/HID) + 1e-6f);
  #pragma unroll
  for(int i=0;i<8;i++){
    int j = tid*8 + i;
    qkv[base + j]       = f2bf(qv[i]*rq*qnw[j]);
    qkv[base + HID + j] = f2bf(kv[i]*rk*knw[j]);
  }
}

// ---------------------------------------------------------------------------
// E2b (after attention): overwrite q/k/v regions with fq/fk/fv.
// ---------------------------------------------------------------------------
__global__ __launch_bounds__(256) void e2b_k(
    bf16* __restrict__ qkv,
    const float* __restrict__ qks, const float* __restrict__ qko)
{
  int s = blockIdx.x, tid = threadIdx.x;
  size_t base = (size_t)s*QKV3;
  float a[8], b[8], vv[8];
  float ga = 0.f, gb2 = 0.f;
  #pragma unroll
  for(int i=0;i<8;i++){
    int j = tid*8 + i;
    float qn = bf2f(qkv[base + j]);
    float kn = bf2f(qkv[base + HID + j]);
    float v  = bf2f(qkv[base + 2*HID + j]);
    a[i] = siluf(qn*qks[2*j]   + qko[2*j]);
    b[i] = siluf(kn*qks[2*j+1] + qko[2*j+1]);
    vv[i] = siluf(v);
    ga += a[i]*a[i]; gb2 += b[i]*b[i];
  }
  ga = wave_sum(ga); gb2 = wave_sum(gb2);
  float iq = 1.f / fmaxf(sqrtf(ga), 1e-12f);
  float ik = 1.f / fmaxf(sqrtf(gb2), 1e-12f);
  #pragma unroll
  for(int i=0;i<8;i++){
    int j = tid*8 + i;
    qkv[base + j]         = f2bf(a[i]*iq);
    qkv[base + HID + j]   = f2bf(b[i]*ik);
    qkv[base + 2*HID + j] = f2bf(vv[i]);
  }
}

// ---------------------------------------------------------------------------
// Sliding-window attention (window 256 incl self), flash-style over 5 key
// tiles of 64. One block = 1 head x 64 queries. Output fp32 into attn (d_out).
// ---------------------------------------------------------------------------
__global__ __launch_bounds__(256) void attn_k(
    const bf16* __restrict__ qkv,
    const float* __restrict__ rc, const float* __restrict__ rs,
    float* __restrict__ attn)
{
  __shared__ __align__(16) bf16  Qs[64][132];
  __shared__ __align__(16) float KVs[64][132];
  const int head = blockIdx.x >> 7;
  const int Q0 = (blockIdx.x & 127) * 64;
  const int tid = threadIdx.x;
  const int hb = head * HD;

  #pragma unroll
  for(int i=0;i<16;i++){
    int e = tid + i*256;
    int rr = e >> 6, d = e & 63;
    int qpos = Q0 + rr;
    size_t b = (size_t)qpos*QKV3 + hb;
    float x1 = bf2f(qkv[b + d]);
    float x2 = bf2f(qkv[b + d + 64]);
    float c = rc[qpos*64 + d], sn = rs[qpos*64 + d];
    Qs[rr][d]      = f2bf(x1*c - x2*sn);
    Qs[rr][d + 64] = f2bf(x2*c + x1*sn);
  }

  const int r = tid >> 2, sub = tid & 3;
  const int qpos = Q0 + r;
  const int lanebase = (tid & 63) & ~3;
  float m = -INFINITY, l = 0.f;
  float O[32];
  #pragma unroll
  for(int q=0;q<32;q++) O[q] = 0.f;

  for(int kt=0; kt<5; kt++){
    const int kb = Q0 - 256 + kt*64;
    __syncthreads();
    #pragma unroll
    for(int i=0;i<16;i++){
      int e = tid + i*256;
      int rr = e >> 6, d = e & 63;
      int kpos = kb + rr;
      float o1 = 0.f, o2 = 0.f;
      if(kpos >= 0){
        size_t b = (size_t)kpos*QKV3 + HID + hb;
        float x1 = bf2f(qkv[b + d]);
        float x2 = bf2f(qkv[b + d + 64]);
        float c = rc[kpos*64 + d], sn = rs[kpos*64 + d];
        o1 = x1*c - x2*sn; o2 = x2*c + x1*sn;
      }
      KVs[rr][d] = o1; KVs[rr][d+64] = o2;
    }
    __syncthreads();

    float sc[16];
    #pragma unroll
    for(int i=0;i<16;i++) sc[i] = 0.f;
    for(int dq=0; dq<32; dq++){
      float q0 = bf2f(Qs[r][4*dq+0]);
      float q1 = bf2f(Qs[r][4*dq+1]);
      float q2 = bf2f(Qs[r][4*dq+2]);
      float q3 = bf2f(Qs[r][4*dq+3]);
      #pragma unroll
      for(int i=0;i<16;i++){
        const float* kr = &KVs[4*i+sub][4*dq];
        sc[i] += q0*kr[0] + q1*kr[1] + q2*kr[2] + q3*kr[3];
      }
    }
    unsigned vmask = 0;
    #pragma unroll
    for(int i=0;i<16;i++){
      int kpos = kb + 4*i + sub;
      bool valid = (kpos >= 0) && (kpos > qpos - 256) && (kpos <= qpos);
      sc[i] = valid ? sc[i]*0.088388347648318447f : -INFINITY;
      vmask |= valid ? (1u<<i) : 0u;
    }
    float tmax = -INFINITY;
    #pragma unroll
    for(int i=0;i<16;i++) tmax = fmaxf(tmax, sc[i]);
    tmax = fmaxf(tmax, __shfl_xor(tmax, 1, 64));
    tmax = fmaxf(tmax, __shfl_xor(tmax, 2, 64));
    float mnew = fmaxf(m, tmax);
    float alpha = (mnew == m) ? 1.f : __expf(m - mnew);
    float p[16];
    float psum = 0.f;
    #pragma unroll
    for(int i=0;i<16;i++){
      float pv = ((vmask >> i) & 1u) ? __expf(sc[i] - mnew) : 0.f;
      p[i] = pv; psum += pv;
    }
    psum += __shfl_xor(psum, 1, 64);
    psum += __shfl_xor(psum, 2, 64);
    l = l*alpha + psum;
    m = mnew;
    #pragma unroll
    for(int q=0;q<32;q++) O[q] *= alpha;

    __syncthreads();
    #pragma unroll
    for(int i=0;i<32;i++){
      int e = tid + i*256;
      int rr = e >> 7, d = e & 127;
      int kpos = kb + rr;
      KVs[rr][d] = (kpos >= 0) ? bf2f(qkv[(size_t)kpos*QKV3 + 2*HID + hb + d]) : 0.f;
    }
    __syncthreads();
    #pragma unroll
    for(int j=0;j<64;j++){
      float pj = __shfl(p[j>>2], lanebase + (j&3), 64);
      const float* vr = &KVs[j][sub*32];
      #pragma unroll
      for(int q=0;q<32;q++) O[q] += pj * vr[q];
    }
  }
  float invl = 1.f / l;
  size_t ob = (size_t)qpos*HID + hb + sub*32;
  #pragma unroll
  for(int q=0;q<32;q++) attn[ob + q] = O[q] * invl;
}

// ---------------------------------------------------------------------------
// TTT elementwise fwd: hid = silu(g)*hm ; opre = silu(qg)*qm (opre -> qg buf)
// ---------------------------------------------------------------------------
__global__ __launch_bounds__(256) void e3_k(
    const bf16* __restrict__ g, const bf16* __restrict__ hm,
    bf16* __restrict__ qg, const bf16* __restrict__ qm,
    bf16* __restrict__ hid)
{
  size_t idx = (size_t)blockIdx.x*256 + threadIdx.x;
  float opre = siluf(bf2f(qg[idx])) * bf2f(qm[idx]);
  hid[idx] = f2bf(siluf(bf2f(g[idx])) * bf2f(hm[idx]));
  qg[idx]  = f2bf(opre);
}

// ---------------------------------------------------------------------------
// TTT backprop elementwise (in place): a0->g, a2->hm, a1->dhid buffer.
// ---------------------------------------------------------------------------
__global__ __launch_bounds__(256) void e4_k(
    bf16* __restrict__ g, bf16* __restrict__ hm, bf16* __restrict__ dhid,
    const bf16* __restrict__ qkv, const float* __restrict__ lrb, int cbase)
{
  size_t idx = (size_t)blockIdx.x*256 + threadIdx.x;
  int h  = (int)(idx >> 20);          // CHUNK_LEN*FD = 2^20
  int ci = (int)((idx >> 9) & 2047);
  int d  = (int)(idx & 511);
  int s  = cbase + ci;
  float l0  = lrb[s*12 + h];
  float l1  = lrb[s*12 + 4 + h];
  float l2v = lrb[s*12 + 8 + h];
  float gg = bf2f(g[idx]), hv = bf2f(hm[idx]), dh = bf2f(dhid[idx]);
  float sg = sigm(gg);
  float silu_g = gg * sg;
  float dhm = dh * silu_g;
  float dg  = dh * hv;
  float dgp = dg * (sg * (1.f + gg * (1.f - sg)));
  float fvv = bf2f(qkv[(size_t)s*QKV3 + 2*HID + h*FD + d]);
  g[idx]    = f2bf(dgp * l0);
  hm[idx]   = f2bf(dhm * l2v);
  dhid[idx] = f2bf(fvv * l1);
}

// ---------------------------------------------------------------------------
// E5 (per chunk): X = attn + rmsnorm(ofc)*ttt_norm_w -> q region of qkv (bf16)
// ---------------------------------------------------------------------------
__global__ __launch_bounds__(256) void e5_k(const float* __restrict__ attn,
    const bf16* __restrict__ ofc, const float* __restrict__ tnw,
    bf16* __restrict__ qkv, int cbase)
{
  int ci = blockIdx.x, tid = threadIdx.x;
  int s = cbase + ci;
  int lane = tid & 63, w = tid >> 6;
  float o[8]; float ss = 0.f;
  size_t ob = ((size_t)w*CHUNK_LEN + ci)*FD + (size_t)lane*8;
  #pragma unroll
  for(int i=0;i<8;i++){ o[i] = bf2f(ofc[ob+i]); ss += o[i]*o[i]; }
  ss = wave_sum(ss);
  float inv = rsqrtf(ss*(1.f/FD) + 1e-6f);
  size_t xb = (size_t)s*QKV3 + w*FD + (size_t)lane*8;
  size_t ab = (size_t)s*HID  + w*FD + (size_t)lane*8;
  #pragma unroll
  for(int i=0;i<8;i++){
    int d = lane*8 + i;
    qkv[xb+i] = f2bf(attn[ab+i] + o[i]*inv*tnw[d]);
  }
}

// ---------------------------------------------------------------------------
extern "C" void kernel_launch(void* const* d_in, const int* in_sizes, int n_in,
                              void* d_out, int out_size, void* d_ws, size_t ws_size,
                              hipStream_t stream)
{
  (void)in_sizes; (void)n_in; (void)out_size;
  const float* hidden   = (const float*)d_in[0];
  const float* qkv_w    = (const float*)d_in[1];
  const float* q_norm_w = (const float*)d_in[2];
  const float* k_norm_w = (const float*)d_in[3];
  const float* qk_scale = (const float*)d_in[4];
  const float* qk_off   = (const float*)d_in[5];
  const float* lr_w     = (const float*)d_in[6];
  const float* lr_b     = (const float*)d_in[7];
  const float* w0_in    = (const float*)d_in[8];
  const float* w1_in    = (const float*)d_in[9];
  const float* w2_in    = (const float*)d_in[10];
  const float* ttt_nw   = (const float*)d_in[11];
  const float* o_proj   = (const float*)d_in[12];
  float* out = (float*)d_out;

  char* p = (char*)d_ws;
  auto alloc = [&](size_t n){ char* r = p; p += (n + 255) & ~(size_t)255; return (void*)r; };

  bf16*  qkv   = (bf16*) alloc((size_t)S_LEN*QKV3*sizeof(bf16));  // raw qkv -> qn/kn/v -> fq/fk/fv -> X in q region
  float* lrb   = (float*)alloc((size_t)S_LEN*12*sizeof(float));
  float* rc    = (float*)alloc((size_t)S_LEN*64*sizeof(float));
  float* rs    = (float*)alloc((size_t)S_LEN*64*sizeof(float));
  float* w0s   = (float*)alloc((size_t)NFW*FD*FD*sizeof(float));
  float* w1s   = (float*)alloc((size_t)NFW*FD*FD*sizeof(float));
  float* w2s   = (float*)alloc((size_t)NFW*FD*FD*sizeof(float));
  bft*   w1tb  = (bft*)  alloc((size_t)NFW*FD*FD*sizeof(bft));          // w1^T bf16 shadow
  bf16*  gb    = (bf16*) alloc((size_t)NFW*CHUNK_LEN*FD*sizeof(bf16));  // g -> a0
  bf16*  hmb   = (bf16*) alloc((size_t)NFW*CHUNK_LEN*FD*sizeof(bf16));  // hm -> a2
  bf16*  qgb   = (bf16*) alloc((size_t)NFW*CHUNK_LEN*FD*sizeof(bf16));  // qg -> opre -> a0T
  bf16*  qmb   = (bf16*) alloc((size_t)NFW*CHUNK_LEN*FD*sizeof(bf16));  // qm -> dhid -> a1
  bf16*  hidb  = (bf16*) alloc((size_t)NFW*CHUNK_LEN*FD*sizeof(bf16));  // hid
  bf16*  ofc   = (bf16*) alloc((size_t)NFW*CHUNK_LEN*FD*sizeof(bf16));  // ofast chunk
  bft*   fkT   = (bft*)  alloc((size_t)NFW*FD*CHUNK_LEN*sizeof(bft));
  bft*   hidT  = (bft*)  alloc((size_t)NFW*FD*CHUNK_LEN*sizeof(bft));
  bft*   a2T   = (bft*)  alloc((size_t)NFW*FD*CHUNK_LEN*sizeof(bft));
  bft*   a1T   = (bft*)  alloc((size_t)NFW*FD*CHUNK_LEN*sizeof(bft));

  // workspace guard: fail cleanly (absmax) instead of faulting if too small
  if ((size_t)(p - (char*)d_ws) > ws_size) return;

  float* attn = out;   // attn lives in d_out until the final projection

  hipMemcpyAsync(w0s, w0_in, (size_t)NFW*FD*FD*sizeof(float), hipMemcpyDeviceToDevice, stream);
  hipMemcpyAsync(w1s, w1_in, (size_t)NFW*FD*FD*sizeof(float), hipMemcpyDeviceToDevice, stream);
  hipMemcpyAsync(w2s, w2_in, (size_t)NFW*FD*FD*sizeof(float), hipMemcpyDeviceToDevice, stream);

  rope_k<<<S_LEN, 64, 0, stream>>>(rc, rs);
  lr_k<<<S_LEN, 256, 0, stream>>>(hidden, lr_w, lr_b, lrb);
  tcw1_k<<<NFW*FD*FD/256, 256, 0, stream>>>(w1_in, w1tb);

  // qkv = hidden @ qkv_w^T -> bf16   (fp32 operands converted in staging)
  mgemm<128,128,0>(stream, hidden, qkv_w, qkv, (bft*)nullptr,
      S_LEN, QKV3, HID, HID, HID, QKV3, 1, 0, 0, 0);

  e2a_k<<<S_LEN, 256, 0, stream>>>(qkv, q_norm_w, k_norm_w);
  attn_k<<<NH*128, 256, 0, stream>>>(qkv, rc, rs, attn);
  e2b_k<<<S_LEN, 256, 0, stream>>>(qkv, qk_scale, qk_off);

  const long sW  = (long)FD*FD;          // head stride in fast weights
  const long sCh = (long)CHUNK_LEN*FD;   // head stride in chunk buffers
  const long sT  = (long)FD*CHUNK_LEN;   // head stride in transposed buffers
  const int  NEL = NFW*CHUNK_LEN*FD/256;
  const dim3 tg(FD/64, CHUNK_LEN/64, NFW);

  for(int c=0; c<NCHUNK; c++){
    const bft* fqc = (const bft*)qkv + (size_t)c*CHUNK_LEN*QKV3;
    const bft* fkc = fqc + HID;
    const bft* fvc = fqc + 2*HID;
    // forward matmuls vs current weights (fp32 masters, converted in staging)
    mgemm<128,128,0>(stream, fkc, w0s, gb,  (bft*)nullptr, CHUNK_LEN, FD, FD, QKV3, FD, FD, NFW, FD, sW, sCh);
    mgemm<128,128,0>(stream, fkc, w2s, hmb, (bft*)nullptr, CHUNK_LEN, FD, FD, QKV3, FD, FD, NFW, FD, sW, sCh);
    mgemm<128,128,0>(stream, fqc, w0s, qgb, (bft*)nullptr, CHUNK_LEN, FD, FD, QKV3, FD, FD, NFW, FD, sW, sCh);
    mgemm<128,128,0>(stream, fqc, w2s, qmb, (bft*)nullptr, CHUNK_LEN, FD, FD, QKV3, FD, FD, NFW, FD, sW, sCh);
    e3_k<<<NEL, 256, 0, stream>>>(gb, hmb, qgb, qmb, hidb);
    // o = opre @ w1^T -> ofc ; dhid = fv @ w1 -> qmb (w1tb = w1^T rows)
    mgemm<128,128,0>(stream, (const bft*)qgb, w1s, ofc, (bft*)nullptr, CHUNK_LEN, FD, FD, FD, FD, FD, NFW, sCh, sW, sCh);
    mgemm<128,128,0>(stream, fvc, (const bft*)w1tb, qmb, (bft*)nullptr, CHUNK_LEN, FD, FD, QKV3, FD, FD, NFW, FD, sW, sCh);
    e4_k<<<NEL, 256, 0, stream>>>(gb, hmb, qmb, qkv, lrb, c*CHUNK_LEN);
    // transposes for the TN update gemms (a0T reuses qgb; opre is dead)
    tr_k<<<tg, 256, 0, stream>>>(fkc,              fkT,        QKV3, FD,  sT);
    tr_k<<<tg, 256, 0, stream>>>((const bft*)hidb, hidT,       FD,   sCh, sT);
    tr_k<<<tg, 256, 0, stream>>>((const bft*)gb,   (bft*)qgb,  FD,   sCh, sT);
    tr_k<<<tg, 256, 0, stream>>>((const bft*)hmb,  a2T,        FD,   sCh, sT);
    tr_k<<<tg, 256, 0, stream>>>((const bft*)qmb,  a1T,        FD,   sCh, sT);
    // weight updates: w += a^T @ b  (NT on transposed operands, fp32 masters)
    mgemm<64,64,2>(stream, (const bft*)qgb, fkT,  w0s, (bft*)nullptr, FD, FD, CHUNK_LEN, CHUNK_LEN, CHUNK_LEN, FD, NFW, sT, sT, sW);
    mgemm<64,64,2>(stream, a2T,             fkT,  w2s, (bft*)nullptr, FD, FD, CHUNK_LEN, CHUNK_LEN, CHUNK_LEN, FD, NFW, sT, sT, sW);
    mgemm<64,64,2>(stream, a1T,             hidT, w1s, w1tb,          FD, FD, CHUNK_LEN, CHUNK_LEN, CHUNK_LEN, FD, NFW, sT, sT, sW);
    // fold this chunk's output into X (q region of qkv)
    e5_k<<<CHUNK_LEN, 256, 0, stream>>>(attn, ofc, ttt_nw, qkv, c*CHUNK_LEN);
  }

  // out = X @ o_proj^T  (X bf16 in q region of qkv, row stride QKV3)
  mgemm<128,128,1>(stream, (const bft*)qkv, o_proj, out, (bft*)nullptr,
      S_LEN, HID, HID, QKV3, HID, HID, 1, 0, 0, 0);
}

// Round 4
// 1979.027 us; speedup vs baseline: 4.2181x; 1.5922x over previous
//
#include <hip/hip_runtime.h>
#include <hip/hip_bf16.h>

typedef __hip_bfloat16 bf16;
typedef __bf16 bft;
typedef bft bf16x8 __attribute__((ext_vector_type(8)));
typedef bft bf16x4 __attribute__((ext_vector_type(4)));
typedef float f32x4 __attribute__((ext_vector_type(4)));

#define S_LEN 8192
#define HID   2048
#define QKV3  6144
#define NH    16
#define HD    128
#define NFW   4
#define FD    512
#define CHUNK_LEN 2048
#define NCHUNK 4
#define BASE_LR_INV (-6.9072552f)   // log(expm1(0.001))
#define BKP 40                      // GEMM LDS K-stride (32 + 8 pad)
#define QKP 136                     // attn Q/K LDS stride (128 + 8)
#define VSP 72                      // attn V^T LDS stride (64 + 8)
#define PSP 76                      // attn P LDS stride (64 + 12): lane-group offsets 0/24/16/8 -> conflict-free

__device__ __forceinline__ float bf2f(bf16 x){ return __bfloat162float(x); }
__device__ __forceinline__ bf16  f2bf(float x){ return __float2bfloat16(x); }
__device__ __forceinline__ float sigm(float x){ return 1.f/(1.f+__expf(-x)); }
__device__ __forceinline__ float siluf(float x){ return x/(1.f+__expf(-x)); }
__device__ __forceinline__ float wave_sum(float v){
  #pragma unroll
  for(int off=32; off; off>>=1) v += __shfl_xor(v, off, 64);
  return v;
}

// ---------------------------------------------------------------------------
// LDS tile staging for GEMM: ROWS x 32 k-slice, bf16 (direct) or fp32
// (convert) source. dst is [ROWS][BKP] bf16.
// ---------------------------------------------------------------------------
template<int ROWS, typename T>
__device__ __forceinline__ void stage_tile(const T* __restrict__ src, long ld,
                                           bft* dst, int tid)
{
  if constexpr (sizeof(T) == 2) {
    #pragma unroll
    for (int i = 0; i < ROWS/64; ++i) {
      int e = tid + i*256;
      int m = e >> 2, k8 = (e & 3) * 8;
      bf16x8 v = *(const bf16x8*)(src + (size_t)m*ld + k8);
      *(bf16x8*)(dst + (size_t)m*BKP + k8) = v;
    }
  } else {
    #pragma unroll
    for (int i = 0; i < ROWS/32; ++i) {
      int e = tid + i*256;
      int m = e >> 3, k4 = (e & 7) * 4;
      const float4 v = *(const float4*)(src + (size_t)m*ld + k4);
      bf16x4 b; b[0]=(bft)v.x; b[1]=(bft)v.y; b[2]=(bft)v.z; b[3]=(bft)v.w;
      *(bf16x4*)(dst + (size_t)m*BKP + k4) = b;
    }
  }
}

// ---------------------------------------------------------------------------
// MFMA NT GEMM: C[M,N] (+)= A[M,K] * B[N,K]^T, fp32 accumulate.
// EPI: 0 = store bf16, 1 = store fp32, 2 = fp32 C += acc (+ optional
// transposed bf16 shadow Ct). Batched over blockIdx.z.
// ---------------------------------------------------------------------------
template<int BM,int BN,int EPI, typename TA, typename TB>
__global__ __launch_bounds__(256) void mgemm_k(
    const TA* __restrict__ A, const TB* __restrict__ B, void* __restrict__ Cv,
    bft* __restrict__ Ct, int K, long lda, long ldb, long ldc,
    long sA, long sB, long sC)
{
  constexpr int AM = BM/32, AN = BN/32;
  __shared__ __align__(16) bft As[BM*BKP];
  __shared__ __align__(16) bft Bs[BN*BKP];
  const int tid = threadIdx.x;
  const int z = blockIdx.z;
  A += (size_t)z * sA;
  B += (size_t)z * sB;
  const size_t m0 = (size_t)blockIdx.y * BM, n0 = (size_t)blockIdx.x * BN;
  const int wv = tid >> 6, lane = tid & 63;
  const int wm = (wv & 1) * (BM/2), wn = (wv >> 1) * (BN/2);
  const int fr = lane & 15, fko = (lane >> 4) * 8;

  f32x4 acc[AM][AN];
  #pragma unroll
  for (int i=0;i<AM;i++)
    #pragma unroll
    for (int j=0;j<AN;j++) acc[i][j] = (f32x4){0.f,0.f,0.f,0.f};

  const TA* Ab = A + m0*lda;
  const TB* Bb = B + n0*ldb;
  for (int kt = 0; kt < K; kt += 32) {
    __syncthreads();
    stage_tile<BM>(Ab + kt, lda, As, tid);
    stage_tile<BN>(Bb + kt, ldb, Bs, tid);
    __syncthreads();
    bf16x8 af[AM], bfv[AN];
    #pragma unroll
    for (int mi=0; mi<AM; mi++)
      af[mi] = *(const bf16x8*)(As + (size_t)(wm + mi*16 + fr)*BKP + fko);
    #pragma unroll
    for (int ni=0; ni<AN; ni++)
      bfv[ni] = *(const bf16x8*)(Bs + (size_t)(wn + ni*16 + fr)*BKP + fko);
    #pragma unroll
    for (int mi=0; mi<AM; mi++)
      #pragma unroll
      for (int ni=0; ni<AN; ni++)
        acc[mi][ni] = __builtin_amdgcn_mfma_f32_16x16x32_bf16(af[mi], bfv[ni], acc[mi][ni], 0, 0, 0);
  }

  const int er = (lane >> 4) * 4;   // C/D: row=(lane>>4)*4+reg, col=lane&15
  const int ec = lane & 15;
  #pragma unroll
  for (int mi=0; mi<AM; mi++){
    #pragma unroll
    for (int ni=0; ni<AN; ni++){
      #pragma unroll
      for (int r=0; r<4; r++){
        size_t row = m0 + wm + mi*16 + er + r;
        size_t col = n0 + wn + ni*16 + ec;
        size_t idx = (size_t)z*sC + row*ldc + col;
        float v = acc[mi][ni][r];
        if constexpr (EPI == 0){
          ((bft*)Cv)[idx] = (bft)v;
        } else if constexpr (EPI == 1){
          ((float*)Cv)[idx] = v;
        } else {
          float nv = ((float*)Cv)[idx] + v;
          ((float*)Cv)[idx] = nv;
          if (Ct) Ct[(size_t)z*FD*FD + col*FD + row] = (bft)nv;
        }
      }
    }
  }
}

template<int BM,int BN,int EPI, typename TA, typename TB>
static inline void mgemm(hipStream_t st, const TA* A, const TB* B, void* C, bft* Ct,
    int M, int N, int K, long lda, long ldb, long ldc,
    int batch, long sA, long sB, long sC)
{
  dim3 g(N/BN, M/BM, batch);
  mgemm_k<BM,BN,EPI,TA,TB><<<g, 256, 0, st>>>(A, B, C, Ct, K, lda, ldb, ldc, sA, sB, sC);
}

// ---------------------------------------------------------------------------
// Batched bf16 transpose: out[z][c][r] = in[z][r][c], R=2048, C=512.
// ---------------------------------------------------------------------------
__global__ __launch_bounds__(256) void tr_k(const bft* __restrict__ in,
    bft* __restrict__ out, long ldin, long sIn, long sOut)
{
  __shared__ __align__(16) bft t[64][72];
  const int c0 = blockIdx.x*64, r0 = blockIdx.y*64;
  in  += (size_t)blockIdx.z * sIn;
  out += (size_t)blockIdx.z * sOut;
  const int tid = threadIdx.x;
  #pragma unroll
  for (int i=0;i<2;i++){
    int e = tid + i*256;
    int r = e >> 3, c8 = (e & 7) * 8;
    *(bf16x8*)&t[r][c8] = *(const bf16x8*)(in + (size_t)(r0+r)*ldin + c0 + c8);
  }
  __syncthreads();
  #pragma unroll
  for (int i=0;i<2;i++){
    int e = tid + i*256;
    int c = e >> 3, r8 = (e & 7) * 8;
    bf16x8 v;
    #pragma unroll
    for (int j=0;j<8;j++) v[j] = t[r8+j][c];
    *(bf16x8*)(out + (size_t)(c0+c)*CHUNK_LEN + r0 + r8) = v;
  }
}

// initial w1^T bf16 shadow: w1tb[z][h][o] = (bf16)w1[z][o][h]
__global__ __launch_bounds__(256) void tcw1_k(const float* __restrict__ w1,
    bft* __restrict__ w1tb)
{
  size_t idx = (size_t)blockIdx.x*256 + threadIdx.x;
  int z = (int)(idx >> 18);
  int h = (int)((idx >> 9) & 511);
  int o = (int)(idx & 511);
  w1tb[idx] = (bft)w1[(size_t)z*FD*FD + (size_t)o*FD + h];
}

// ---------------------------------------------------------------------------
// v^T for attention PV: vT[h][d][s] = v[s][h*128+d] (raw v region of qkv).
// grid (S/64, NH), 256 threads.
// ---------------------------------------------------------------------------
__global__ __launch_bounds__(256) void vt_k(const bf16* __restrict__ qkv,
    bft* __restrict__ vT)
{
  __shared__ __align__(16) bft t[64*QKP];   // [s][d]
  const int s0 = blockIdx.x * 64;
  const int h  = blockIdx.y;
  const int tid = threadIdx.x;
  #pragma unroll
  for (int i=0;i<4;i++){
    int e = tid + i*256;
    int rr = e >> 4, doff = (e & 15) * 8;
    *(bf16x8*)(t + rr*QKP + doff) =
        *(const bf16x8*)((const bft*)qkv + (size_t)(s0+rr)*QKV3 + 2*HID + h*HD + doff);
  }
  __syncthreads();
  #pragma unroll
  for (int it=0; it<4; it++){
    int d = (tid >> 3) + it*32;
    int so8 = (tid & 7) * 8;
    bf16x8 v;
    #pragma unroll
    for (int j=0;j<8;j++) v[j] = t[(so8+j)*QKP + d];
    *(bf16x8*)(vT + ((size_t)(h*HD + d))*S_LEN + s0 + so8) = v;
  }
}

// ---------------------------------------------------------------------------
// RoPE cos/sin tables
// ---------------------------------------------------------------------------
__global__ void rope_k(float* __restrict__ rc, float* __restrict__ rs){
  int pos = blockIdx.x, d = threadIdx.x;
  float inv = 1.f / powf(500000.0f, (float)d * (1.0f/64.0f));
  float ang = (float)pos * inv;
  rc[pos*64+d] = cosf(ang);
  rs[pos*64+d] = sinf(ang);
}

// ---------------------------------------------------------------------------
// per-token learning rates
// ---------------------------------------------------------------------------
__global__ __launch_bounds__(256) void lr_k(const float* __restrict__ hidden,
    const float* __restrict__ lr_w, const float* __restrict__ lr_b,
    float* __restrict__ lro)
{
  __shared__ float hrow[HID];
  __shared__ float red[4][12];
  int s = blockIdx.x, tid = threadIdx.x;
  for(int i=0;i<HID/256;i++) hrow[tid+256*i] = hidden[(size_t)s*HID + tid + 256*i];
  __syncthreads();
  float part[12];
  #pragma unroll
  for(int o=0;o<12;o++) part[o]=0.f;
  for(int i=0;i<HID/256;i++){
    int j = tid + 256*i;
    float h = hrow[j];
    #pragma unroll
    for(int o=0;o<12;o++) part[o] += h * lr_w[o*HID + j];
  }
  int lane = tid & 63, w = tid >> 6;
  #pragma unroll
  for(int o=0;o<12;o++){
    float v = wave_sum(part[o]);
    if(lane==0) red[w][o] = v;
  }
  __syncthreads();
  if(tid < 12){
    float v = red[0][tid]+red[1][tid]+red[2][tid]+red[3][tid] + lr_b[tid] + BASE_LR_INV;
    float sp = (v > 20.f) ? v : log1pf(expf(v));
    lro[s*12 + tid] = sp;
  }
}

// ---------------------------------------------------------------------------
// E2a: per-token rmsnorm(q), rmsnorm(k), in place in qkv (bf16).
// ---------------------------------------------------------------------------
__global__ __launch_bounds__(256) void e2a_k(
    bf16* __restrict__ qkv,
    const float* __restrict__ qnw, const float* __restrict__ knw)
{
  __shared__ float red[8];
  int s = blockIdx.x, tid = threadIdx.x;
  int lane = tid & 63, w = tid >> 6;
  float qv[8], kv[8];
  float sq = 0.f, sk = 0.f;
  size_t base = (size_t)s*QKV3;
  #pragma unroll
  for(int i=0;i<8;i++){
    int j = tid*8 + i;
    qv[i] = bf2f(qkv[base + j]);
    kv[i] = bf2f(qkv[base + HID + j]);
    sq += qv[i]*qv[i]; sk += kv[i]*kv[i];
  }
  sq = wave_sum(sq); sk = wave_sum(sk);
  if(lane==0){ red[w] = sq; red[4+w] = sk; }
  __syncthreads();
  float rq = rsqrtf((red[0]+red[1]+red[2]+red[3])*(1.f/HID) + 1e-6f);
  float rk = rsqrtf((red[4]+red[5]+red[6]+red[7])*(1.f/HID) + 1e-6f);
  #pragma unroll
  for(int i=0;i<8;i++){
    int j = tid*8 + i;
    qkv[base + j]       = f2bf(qv[i]*rq*qnw[j]);
    qkv[base + HID + j] = f2bf(kv[i]*rk*knw[j]);
  }
}

// ---------------------------------------------------------------------------
// E2b (after attention): overwrite q/k/v regions with fq/fk/fv.
// ---------------------------------------------------------------------------
__global__ __launch_bounds__(256) void e2b_k(
    bf16* __restrict__ qkv,
    const float* __restrict__ qks, const float* __restrict__ qko)
{
  int s = blockIdx.x, tid = threadIdx.x;
  size_t base = (size_t)s*QKV3;
  float a[8], b[8], vv[8];
  float ga = 0.f, gb2 = 0.f;
  #pragma unroll
  for(int i=0;i<8;i++){
    int j = tid*8 + i;
    float qn = bf2f(qkv[base + j]);
    float kn = bf2f(qkv[base + HID + j]);
    float v  = bf2f(qkv[base + 2*HID + j]);
    a[i] = siluf(qn*qks[2*j]   + qko[2*j]);
    b[i] = siluf(kn*qks[2*j+1] + qko[2*j+1]);
    vv[i] = siluf(v);
    ga += a[i]*a[i]; gb2 += b[i]*b[i];
  }
  ga = wave_sum(ga); gb2 = wave_sum(gb2);
  float iq = 1.f / fmaxf(sqrtf(ga), 1e-12f);
  float ik = 1.f / fmaxf(sqrtf(gb2), 1e-12f);
  #pragma unroll
  for(int i=0;i<8;i++){
    int j = tid*8 + i;
    qkv[base + j]         = f2bf(a[i]*iq);
    qkv[base + HID + j]   = f2bf(b[i]*ik);
    qkv[base + 2*HID + j] = f2bf(vv[i]);
  }
}

// ---------------------------------------------------------------------------
// MFMA sliding-window attention (window 256 incl self). One block = 1 head
// x 64 queries, 4 waves; wave w owns query rows 16w..16w+15. 5 key tiles of
// 64 (negative tiles skipped block-uniformly). QK^T and PV on
// mfma_f32_16x16x32_bf16; P routed through LDS (C/D -> A layout).
// ---------------------------------------------------------------------------
__global__ __launch_bounds__(256) void attn_k(
    const bf16* __restrict__ qkv, const bft* __restrict__ vT,
    const float* __restrict__ rc, const float* __restrict__ rs,
    float* __restrict__ attn)
{
  __shared__ __align__(16) bft Qs[64*QKP];
  __shared__ __align__(16) bft Ks[64*QKP];
  __shared__ __align__(16) bft Vs[128*VSP];
  __shared__ __align__(16) bft Ps[64*PSP];
  const int head = blockIdx.x >> 7;
  const int Q0 = (blockIdx.x & 127) * 64;
  const int tid = threadIdx.x;
  const int hb = head * HD;
  const int lane = tid & 63;
  const int wm = (tid >> 6) * 16;
  const int fr = lane & 15, fko = (lane >> 4) * 8;
  const int rbase = (lane >> 4) * 4;

  // stage Q (roped), once
  #pragma unroll
  for(int i=0;i<16;i++){
    int e = tid + i*256;
    int rr = e >> 6, d = e & 63;
    int qpos = Q0 + rr;
    size_t b = (size_t)qpos*QKV3 + hb;
    float x1 = bf2f(qkv[b + d]);
    float x2 = bf2f(qkv[b + d + 64]);
    float c = rc[qpos*64 + d], sn = rs[qpos*64 + d];
    Qs[rr*QKP + d]      = (bft)(x1*c - x2*sn);
    Qs[rr*QKP + d + 64] = (bft)(x2*c + x1*sn);
  }
  __syncthreads();
  bf16x8 qf[4];
  #pragma unroll
  for (int kk=0;kk<4;kk++)
    qf[kk] = *(const bf16x8*)(Qs + (wm+fr)*QKP + kk*32 + fko);

  f32x4 Ot[8];
  #pragma unroll
  for (int i=0;i<8;i++) Ot[i] = (f32x4){0.f,0.f,0.f,0.f};
  float m4[4], l4[4];
  #pragma unroll
  for (int r=0;r<4;r++){ m4[r] = -INFINITY; l4[r] = 0.f; }

  for (int kt=0; kt<5; kt++){
    const int kb = Q0 - 256 + kt*64;
    if (kb < 0) continue;            // block-uniform
    __syncthreads();                 // all waves done with previous Ks/Vs
    // stage K (roped)
    #pragma unroll
    for(int i=0;i<16;i++){
      int e = tid + i*256;
      int rr = e >> 6, d = e & 63;
      int kpos = kb + rr;
      size_t b = (size_t)kpos*QKV3 + HID + hb;
      float x1 = bf2f(qkv[b + d]);
      float x2 = bf2f(qkv[b + d + 64]);
      float c = rc[kpos*64 + d], sn = rs[kpos*64 + d];
      Ks[rr*QKP + d]      = (bft)(x1*c - x2*sn);
      Ks[rr*QKP + d + 64] = (bft)(x2*c + x1*sn);
    }
    // stage V^T tile [dim][key]
    {
      int d = tid >> 1, koff = (tid & 1) * 32;
      const bft* vrow = vT + ((size_t)(hb + d))*S_LEN + kb + koff;
      bft* lrow = Vs + d*VSP + koff;
      #pragma unroll
      for (int j8=0;j8<4;j8++)
        *(bf16x8*)(lrow + j8*8) = *(const bf16x8*)(vrow + j8*8);
    }
    __syncthreads();

    // S = Q K^T (this wave's 16 rows x 64 keys)
    f32x4 st[4];
    #pragma unroll
    for (int nt=0;nt<4;nt++){
      f32x4 acc = (f32x4){0.f,0.f,0.f,0.f};
      #pragma unroll
      for (int kk=0;kk<4;kk++){
        bf16x8 kf = *(const bf16x8*)(Ks + (nt*16+fr)*QKP + kk*32 + fko);
        acc = __builtin_amdgcn_mfma_f32_16x16x32_bf16(qf[kk], kf, acc, 0, 0, 0);
      }
      st[nt] = acc;
    }

    // mask + online softmax, per reg-row r (rows shared across 16-lane groups)
    float pv[4][4];
    #pragma unroll
    for (int r=0;r<4;r++){
      int qpos = Q0 + wm + rbase + r;
      float sm[4];
      float mx = -INFINITY;
      #pragma unroll
      for (int nt=0;nt<4;nt++){
        int kpos = kb + nt*16 + fr;
        bool valid = (kpos > qpos - 256) && (kpos <= qpos);
        float s = valid ? st[nt][r] * 0.088388347648318447f : -INFINITY;
        sm[nt] = s;
        mx = fmaxf(mx, s);
      }
      mx = fmaxf(mx, __shfl_xor(mx, 1, 64));
      mx = fmaxf(mx, __shfl_xor(mx, 2, 64));
      mx = fmaxf(mx, __shfl_xor(mx, 4, 64));
      mx = fmaxf(mx, __shfl_xor(mx, 8, 64));
      float mnew = fmaxf(m4[r], mx);
      float alpha = (mnew == -INFINITY) ? 1.f : __expf(m4[r] - mnew);
      float ps = 0.f;
      #pragma unroll
      for (int nt=0;nt<4;nt++){
        float p = (sm[nt] == -INFINITY) ? 0.f : __expf(sm[nt] - mnew);
        pv[nt][r] = p;
        ps += p;
      }
      ps += __shfl_xor(ps, 1, 64);
      ps += __shfl_xor(ps, 2, 64);
      ps += __shfl_xor(ps, 4, 64);
      ps += __shfl_xor(ps, 8, 64);
      l4[r] = l4[r]*alpha + ps;
      m4[r] = mnew;
      #pragma unroll
      for (int ct=0;ct<8;ct++) Ot[ct][r] *= alpha;
    }

    // P -> LDS (wave-private rows), then PV accumulate
    #pragma unroll
    for (int r=0;r<4;r++){
      int row = wm + rbase + r;
      #pragma unroll
      for (int nt=0;nt<4;nt++)
        Ps[row*PSP + nt*16 + fr] = (bft)pv[nt][r];
    }
    bf16x8 af[2];
    #pragma unroll
    for (int kk=0;kk<2;kk++){
      const bft* pp = Ps + (wm+fr)*PSP + kk*32 + fko;
      bf16x4 lo = *(const bf16x4*)pp;
      bf16x4 hi = *(const bf16x4*)(pp+4);
      bf16x8 a;
      #pragma unroll
      for (int j=0;j<4;j++){ a[j]=lo[j]; a[j+4]=hi[j]; }
      af[kk]=a;
    }
    #pragma unroll
    for (int ct=0;ct<8;ct++)
      #pragma unroll
      for (int kk=0;kk<2;kk++){
        bf16x8 bv = *(const bf16x8*)(Vs + (ct*16+fr)*VSP + kk*32 + fko);
        Ot[ct] = __builtin_amdgcn_mfma_f32_16x16x32_bf16(af[kk], bv, Ot[ct], 0, 0, 0);
      }
  }

  // epilogue: O / l
  #pragma unroll
  for (int r=0;r<4;r++){
    float invl = 1.f / l4[r];
    int qpos = Q0 + wm + rbase + r;
    size_t ob = (size_t)qpos*HID + hb;
    #pragma unroll
    for (int ct=0;ct<8;ct++)
      attn[ob + ct*16 + fr] = Ot[ct][r] * invl;
  }
}

// ---------------------------------------------------------------------------
// TTT elementwise fwd: hid = silu(g)*hm ; opre = silu(qg)*qm (opre -> qg buf)
// ---------------------------------------------------------------------------
__global__ __launch_bounds__(256) void e3_k(
    const bf16* __restrict__ g, const bf16* __restrict__ hm,
    bf16* __restrict__ qg, const bf16* __restrict__ qm,
    bf16* __restrict__ hid)
{
  size_t idx = (size_t)blockIdx.x*256 + threadIdx.x;
  float opre = siluf(bf2f(qg[idx])) * bf2f(qm[idx]);
  hid[idx] = f2bf(siluf(bf2f(g[idx])) * bf2f(hm[idx]));
  qg[idx]  = f2bf(opre);
}

// ---------------------------------------------------------------------------
// TTT backprop elementwise (in place): a0->g, a2->hm, a1->dhid buffer.
// ---------------------------------------------------------------------------
__global__ __launch_bounds__(256) void e4_k(
    bf16* __restrict__ g, bf16* __restrict__ hm, bf16* __restrict__ dhid,
    const bf16* __restrict__ qkv, const float* __restrict__ lrb, int cbase)
{
  size_t idx = (size_t)blockIdx.x*256 + threadIdx.x;
  int h  = (int)(idx >> 20);
  int ci = (int)((idx >> 9) & 2047);
  int d  = (int)(idx & 511);
  int s  = cbase + ci;
  float l0  = lrb[s*12 + h];
  float l1  = lrb[s*12 + 4 + h];
  float l2v = lrb[s*12 + 8 + h];
  float gg = bf2f(g[idx]), hv = bf2f(hm[idx]), dh = bf2f(dhid[idx]);
  float sg = sigm(gg);
  float silu_g = gg * sg;
  float dhm = dh * silu_g;
  float dg  = dh * hv;
  float dgp = dg * (sg * (1.f + gg * (1.f - sg)));
  float fvv = bf2f(qkv[(size_t)s*QKV3 + 2*HID + h*FD + d]);
  g[idx]    = f2bf(dgp * l0);
  hm[idx]   = f2bf(dhm * l2v);
  dhid[idx] = f2bf(fvv * l1);
}

// ---------------------------------------------------------------------------
// E5 (per chunk): X = attn + rmsnorm(ofc)*ttt_norm_w -> q region of qkv
// ---------------------------------------------------------------------------
__global__ __launch_bounds__(256) void e5_k(const float* __restrict__ attn,
    const bf16* __restrict__ ofc, const float* __restrict__ tnw,
    bf16* __restrict__ qkv, int cbase)
{
  int ci = blockIdx.x, tid = threadIdx.x;
  int s = cbase + ci;
  int lane = tid & 63, w = tid >> 6;
  float o[8]; float ss = 0.f;
  size_t ob = ((size_t)w*CHUNK_LEN + ci)*FD + (size_t)lane*8;
  #pragma unroll
  for(int i=0;i<8;i++){ o[i] = bf2f(ofc[ob+i]); ss += o[i]*o[i]; }
  ss = wave_sum(ss);
  float inv = rsqrtf(ss*(1.f/FD) + 1e-6f);
  size_t xb = (size_t)s*QKV3 + w*FD + (size_t)lane*8;
  size_t ab = (size_t)s*HID  + w*FD + (size_t)lane*8;
  #pragma unroll
  for(int i=0;i<8;i++){
    int d = lane*8 + i;
    qkv[xb+i] = f2bf(attn[ab+i] + o[i]*inv*tnw[d]);
  }
}

// ---------------------------------------------------------------------------
extern "C" void kernel_launch(void* const* d_in, const int* in_sizes, int n_in,
                              void* d_out, int out_size, void* d_ws, size_t ws_size,
                              hipStream_t stream)
{
  (void)in_sizes; (void)n_in; (void)out_size;
  const float* hidden   = (const float*)d_in[0];
  const float* qkv_w    = (const float*)d_in[1];
  const float* q_norm_w = (const float*)d_in[2];
  const float* k_norm_w = (const float*)d_in[3];
  const float* qk_scale = (const float*)d_in[4];
  const float* qk_off   = (const float*)d_in[5];
  const float* lr_w     = (const float*)d_in[6];
  const float* lr_b     = (const float*)d_in[7];
  const float* w0_in    = (const float*)d_in[8];
  const float* w1_in    = (const float*)d_in[9];
  const float* w2_in    = (const float*)d_in[10];
  const float* ttt_nw   = (const float*)d_in[11];
  const float* o_proj   = (const float*)d_in[12];
  float* out = (float*)d_out;

  char* p = (char*)d_ws;
  auto alloc = [&](size_t n){ char* r = p; p += (n + 255) & ~(size_t)255; return (void*)r; };

  bf16*  qkv   = (bf16*) alloc((size_t)S_LEN*QKV3*sizeof(bf16));
  float* lrb   = (float*)alloc((size_t)S_LEN*12*sizeof(float));
  float* rc    = (float*)alloc((size_t)S_LEN*64*sizeof(float));
  float* rs    = (float*)alloc((size_t)S_LEN*64*sizeof(float));
  float* w0s   = (float*)alloc((size_t)NFW*FD*FD*sizeof(float));
  float* w1s   = (float*)alloc((size_t)NFW*FD*FD*sizeof(float));
  float* w2s   = (float*)alloc((size_t)NFW*FD*FD*sizeof(float));
  bft*   w1tb  = (bft*)  alloc((size_t)NFW*FD*FD*sizeof(bft));
  bf16*  gb    = (bf16*) alloc((size_t)NFW*CHUNK_LEN*FD*sizeof(bf16));
  bf16*  hmb   = (bf16*) alloc((size_t)NFW*CHUNK_LEN*FD*sizeof(bf16));
  bf16*  qgb   = (bf16*) alloc((size_t)NFW*CHUNK_LEN*FD*sizeof(bf16));
  bf16*  qmb   = (bf16*) alloc((size_t)NFW*CHUNK_LEN*FD*sizeof(bf16));
  bf16*  hidb  = (bf16*) alloc((size_t)NFW*CHUNK_LEN*FD*sizeof(bf16));
  bf16*  ofc   = (bf16*) alloc((size_t)NFW*CHUNK_LEN*FD*sizeof(bf16));
  bft*   fkT   = (bft*)  alloc((size_t)NFW*FD*CHUNK_LEN*sizeof(bft));
  bft*   hidT  = (bft*)  alloc((size_t)NFW*FD*CHUNK_LEN*sizeof(bft));
  bft*   a2T   = (bft*)  alloc((size_t)NFW*FD*CHUNK_LEN*sizeof(bft));
  bft*   a1T   = (bft*)  alloc((size_t)NFW*FD*CHUNK_LEN*sizeof(bft));

  if ((size_t)(p - (char*)d_ws) > ws_size) return;

  // vT (16*128*8192 bf16 = 33.5 MB) aliases fkT..a1T (4 x 8.39 MB,
  // contiguous): vT is dead before the chunk loop's first tr_k writes fkT.
  bft* vT = fkT;

  float* attn = out;   // attn lives in d_out until the final projection

  hipMemcpyAsync(w0s, w0_in, (size_t)NFW*FD*FD*sizeof(float), hipMemcpyDeviceToDevice, stream);
  hipMemcpyAsync(w1s, w1_in, (size_t)NFW*FD*FD*sizeof(float), hipMemcpyDeviceToDevice, stream);
  hipMemcpyAsync(w2s, w2_in, (size_t)NFW*FD*FD*sizeof(float), hipMemcpyDeviceToDevice, stream);

  rope_k<<<S_LEN, 64, 0, stream>>>(rc, rs);
  lr_k<<<S_LEN, 256, 0, stream>>>(hidden, lr_w, lr_b, lrb);
  tcw1_k<<<NFW*FD*FD/256, 256, 0, stream>>>(w1_in, w1tb);

  // qkv = hidden @ qkv_w^T -> bf16
  mgemm<128,128,0>(stream, hidden, qkv_w, qkv, (bft*)nullptr,
      S_LEN, QKV3, HID, HID, HID, QKV3, 1, 0, 0, 0);

  e2a_k<<<S_LEN, 256, 0, stream>>>(qkv, q_norm_w, k_norm_w);
  vt_k<<<dim3(S_LEN/64, NH), 256, 0, stream>>>(qkv, vT);
  attn_k<<<NH*128, 256, 0, stream>>>(qkv, vT, rc, rs, attn);
  e2b_k<<<S_LEN, 256, 0, stream>>>(qkv, qk_scale, qk_off);

  const long sW  = (long)FD*FD;
  const long sCh = (long)CHUNK_LEN*FD;
  const long sT  = (long)FD*CHUNK_LEN;
  const int  NEL = NFW*CHUNK_LEN*FD/256;
  const dim3 tg(FD/64, CHUNK_LEN/64, NFW);

  for(int c=0; c<NCHUNK; c++){
    const bft* fqc = (const bft*)qkv + (size_t)c*CHUNK_LEN*QKV3;
    const bft* fkc = fqc + HID;
    const bft* fvc = fqc + 2*HID;
    mgemm<128,128,0>(stream, fkc, w0s, gb,  (bft*)nullptr, CHUNK_LEN, FD, FD, QKV3, FD, FD, NFW, FD, sW, sCh);
    mgemm<128,128,0>(stream, fkc, w2s, hmb, (bft*)nullptr, CHUNK_LEN, FD, FD, QKV3, FD, FD, NFW, FD, sW, sCh);
    mgemm<128,128,0>(stream, fqc, w0s, qgb, (bft*)nullptr, CHUNK_LEN, FD, FD, QKV3, FD, FD, NFW, FD, sW, sCh);
    mgemm<128,128,0>(stream, fqc, w2s, qmb, (bft*)nullptr, CHUNK_LEN, FD, FD, QKV3, FD, FD, NFW, FD, sW, sCh);
    e3_k<<<NEL, 256, 0, stream>>>(gb, hmb, qgb, qmb, hidb);
    mgemm<128,128,0>(stream, (const bft*)qgb, w1s, ofc, (bft*)nullptr, CHUNK_LEN, FD, FD, FD, FD, FD, NFW, sCh, sW, sCh);
    mgemm<128,128,0>(stream, fvc, (const bft*)w1tb, qmb, (bft*)nullptr, CHUNK_LEN, FD, FD, QKV3, FD, FD, NFW, FD, sW, sCh);
    e4_k<<<NEL, 256, 0, stream>>>(gb, hmb, qmb, qkv, lrb, c*CHUNK_LEN);
    tr_k<<<tg, 256, 0, stream>>>(fkc,              fkT,        QKV3, FD,  sT);
    tr_k<<<tg, 256, 0, stream>>>((const bft*)hidb, hidT,       FD,   sCh, sT);
    tr_k<<<tg, 256, 0, stream>>>((const bft*)gb,   (bft*)qgb,  FD,   sCh, sT);
    tr_k<<<tg, 256, 0, stream>>>((const bft*)hmb,  a2T,        FD,   sCh, sT);
    tr_k<<<tg, 256, 0, stream>>>((const bft*)qmb,  a1T,        FD,   sCh, sT);
    mgemm<64,64,2>(stream, (const bft*)qgb, fkT,  w0s, (bft*)nullptr, FD, FD, CHUNK_LEN, CHUNK_LEN, CHUNK_LEN, FD, NFW, sT, sT, sW);
    mgemm<64,64,2>(stream, a2T,             fkT,  w2s, (bft*)nullptr, FD, FD, CHUNK_LEN, CHUNK_LEN, CHUNK_LEN, FD, NFW, sT, sT, sW);
    mgemm<64,64,2>(stream, a1T,             hidT, w1s, w1tb,          FD, FD, CHUNK_LEN, CHUNK_LEN, CHUNK_LEN, FD, NFW, sT, sT, sW);
    e5_k<<<CHUNK_LEN, 256, 0, stream>>>(attn, ofc, ttt_nw, qkv, c*CHUNK_LEN);
  }

  mgemm<128,128,1>(stream, (const bft*)qkv, o_proj, out, (bft*)nullptr,
      S_LEN, HID, HID, QKV3, HID, HID, 1, 0, 0, 0);
}

// Round 5
// 1800.542 us; speedup vs baseline: 4.6363x; 1.0991x over previous
//
#include <hip/hip_runtime.h>
#include <hip/hip_bf16.h>

typedef __hip_bfloat16 bf16;
typedef __bf16 bft;
typedef bft bf16x8 __attribute__((ext_vector_type(8)));
typedef bft bf16x4 __attribute__((ext_vector_type(4)));
typedef float f32x4 __attribute__((ext_vector_type(4)));

#define S_LEN 8192
#define HID   2048
#define QKV3  6144
#define NH    16
#define HD    128
#define NFW   4
#define FD    512
#define CHUNK_LEN 2048
#define NCHUNK 4
#define BASE_LR_INV (-6.9072552f)   // log(expm1(0.001))
#define QKP 136                     // attn Q/K LDS stride (128 + 8)
#define VSP 72                      // attn V^T LDS stride (64 + 8)
#define PSP 76                      // attn P LDS stride (64 + 12)

__device__ __forceinline__ float bf2f(bf16 x){ return __bfloat162float(x); }
__device__ __forceinline__ bf16  f2bf(float x){ return __float2bfloat16(x); }
__device__ __forceinline__ float sigm(float x){ return 1.f/(1.f+__expf(-x)); }
__device__ __forceinline__ float siluf(float x){ return x/(1.f+__expf(-x)); }
__device__ __forceinline__ float wave_sum(float v){
  #pragma unroll
  for(int off=32; off; off>>=1) v += __shfl_xor(v, off, 64);
  return v;
}

// ---------------------------------------------------------------------------
// GEMM LDS tile staging, swizzled layout.
// Tile: ROWS x 32 bf16, unpadded [row][32]; physical col-slot c (8 elems)
// holds logical col-group g = c ^ ((row>>1)&3).
// bf16 source: global_load_lds 16B/lane (lane -> row=lane>>2, c=lane&3;
//   LDS dest = wave-uniform base + lane*16 => exactly (row,c) slot).
// fp32 source: VGPR load+convert, write same swizzled layout.
// ---------------------------------------------------------------------------
template<int ROWS, typename T>
__device__ __forceinline__ void stage(const T* __restrict__ src, long ld,
                                      bft* dst, int tid)
{
  if constexpr (sizeof(T) == 2) {
    const int lane = tid & 63, wv = tid >> 6;
    #pragma unroll
    for (int i = 0; i < ROWS/64; ++i) {
      const int r0 = wv*16 + i*64;               // wave-uniform
      const int row = r0 + (lane >> 2);
      const int g = (lane & 3) ^ ((row >> 1) & 3);
      const bft* gp = (const bft*)src + (size_t)row*ld + g*8;
      bft* lp = dst + (size_t)r0*32;
      __builtin_amdgcn_global_load_lds(
          (const __attribute__((address_space(1))) void*)gp,
          (__attribute__((address_space(3))) void*)lp, 16, 0, 0);
    }
  } else {
    #pragma unroll
    for (int i = 0; i < ROWS/64; ++i) {
      const int e = tid + i*256;
      const int row = e >> 2, c = e & 3;
      const int g = c ^ ((row >> 1) & 3);
      const float* sp = (const float*)src + (size_t)row*ld + g*8;
      const float4 v0 = *(const float4*)sp;
      const float4 v1 = *(const float4*)(sp + 4);
      bf16x8 b;
      b[0]=(bft)v0.x; b[1]=(bft)v0.y; b[2]=(bft)v0.z; b[3]=(bft)v0.w;
      b[4]=(bft)v1.x; b[5]=(bft)v1.y; b[6]=(bft)v1.z; b[7]=(bft)v1.w;
      *(bf16x8*)(dst + (size_t)row*32 + c*8) = b;
    }
  }
}

// ---------------------------------------------------------------------------
// MFMA NT GEMM: C[M,N] (+)= A[M,K] * B[N,K]^T, fp32 accumulate.
// EPI: 0 = store bf16, 1 = store fp32, 2 = fp32 C += acc (+ optional
// transposed bf16 shadow Ct). Batched over blockIdx.z.
// ---------------------------------------------------------------------------
template<int BM,int BN,int EPI, typename TA, typename TB>
__global__ __launch_bounds__(256) void mgemm_k(
    const TA* __restrict__ A, const TB* __restrict__ B, void* __restrict__ Cv,
    bft* __restrict__ Ct, int K, long lda, long ldb, long ldc,
    long sA, long sB, long sC)
{
  constexpr int AM = BM/32, AN = BN/32;
  __shared__ __align__(16) bft As[BM*32];
  __shared__ __align__(16) bft Bs[BN*32];
  const int tid = threadIdx.x;
  const int z = blockIdx.z;
  A += (size_t)z * sA;
  B += (size_t)z * sB;
  const size_t m0 = (size_t)blockIdx.y * BM, n0 = (size_t)blockIdx.x * BN;
  const int wv = tid >> 6, lane = tid & 63;
  const int wm = (wv & 1) * (BM/2), wn = (wv >> 1) * (BN/2);
  const int fr = lane & 15;
  const int fsw = ((lane >> 4) ^ ((fr >> 1) & 3)) * 8;   // swizzled frag col

  f32x4 acc[AM][AN];
  #pragma unroll
  for (int i=0;i<AM;i++)
    #pragma unroll
    for (int j=0;j<AN;j++) acc[i][j] = (f32x4){0.f,0.f,0.f,0.f};

  const TA* Ab = A + m0*lda;
  const TB* Bb = B + n0*ldb;
  for (int kt = 0; kt < K; kt += 32) {
    __syncthreads();
    stage<BM>(Ab + kt, lda, As, tid);
    stage<BN>(Bb + kt, ldb, Bs, tid);
    __syncthreads();
    bf16x8 af[AM], bfv[AN];
    #pragma unroll
    for (int mi=0; mi<AM; mi++)
      af[mi] = *(const bf16x8*)(As + (size_t)(wm + mi*16 + fr)*32 + fsw);
    #pragma unroll
    for (int ni=0; ni<AN; ni++)
      bfv[ni] = *(const bf16x8*)(Bs + (size_t)(wn + ni*16 + fr)*32 + fsw);
    #pragma unroll
    for (int mi=0; mi<AM; mi++)
      #pragma unroll
      for (int ni=0; ni<AN; ni++)
        acc[mi][ni] = __builtin_amdgcn_mfma_f32_16x16x32_bf16(af[mi], bfv[ni], acc[mi][ni], 0, 0, 0);
  }

  const int er = (lane >> 4) * 4;   // C/D: row=(lane>>4)*4+reg, col=lane&15
  const int ec = lane & 15;
  #pragma unroll
  for (int mi=0; mi<AM; mi++){
    #pragma unroll
    for (int ni=0; ni<AN; ni++){
      #pragma unroll
      for (int r=0; r<4; r++){
        size_t row = m0 + wm + mi*16 + er + r;
        size_t col = n0 + wn + ni*16 + ec;
        size_t idx = (size_t)z*sC + row*ldc + col;
        float v = acc[mi][ni][r];
        if constexpr (EPI == 0){
          ((bft*)Cv)[idx] = (bft)v;
        } else if constexpr (EPI == 1){
          ((float*)Cv)[idx] = v;
        } else {
          float nv = ((float*)Cv)[idx] + v;
          ((float*)Cv)[idx] = nv;
          if (Ct) Ct[(size_t)z*FD*FD + col*FD + row] = (bft)nv;
        }
      }
    }
  }
}

template<int BM,int BN,int EPI, typename TA, typename TB>
static inline void mgemm(hipStream_t st, const TA* A, const TB* B, void* C, bft* Ct,
    int M, int N, int K, long lda, long ldb, long ldc,
    int batch, long sA, long sB, long sC)
{
  dim3 g(N/BN, M/BM, batch);
  mgemm_k<BM,BN,EPI,TA,TB><<<g, 256, 0, st>>>(A, B, C, Ct, K, lda, ldb, ldc, sA, sB, sC);
}

// ---------------------------------------------------------------------------
// fp32 -> bf16 bulk convert (8 elems/thread); n must divide 2048.
// ---------------------------------------------------------------------------
__global__ __launch_bounds__(256) void cvt_k(const float* __restrict__ s,
    bft* __restrict__ d)
{
  size_t i = ((size_t)blockIdx.x*256 + threadIdx.x) * 8;
  const float4 v0 = *(const float4*)(s + i);
  const float4 v1 = *(const float4*)(s + i + 4);
  bf16x8 b;
  b[0]=(bft)v0.x; b[1]=(bft)v0.y; b[2]=(bft)v0.z; b[3]=(bft)v0.w;
  b[4]=(bft)v1.x; b[5]=(bft)v1.y; b[6]=(bft)v1.z; b[7]=(bft)v1.w;
  *(bf16x8*)(d + i) = b;
}

// ---------------------------------------------------------------------------
// Batched bf16 transpose: out[z][c][r] = in[z][r][c], R=2048, C=512.
// ---------------------------------------------------------------------------
__global__ __launch_bounds__(256) void tr_k(const bft* __restrict__ in,
    bft* __restrict__ out, long ldin, long sIn, long sOut)
{
  __shared__ __align__(16) bft t[64][72];
  const int c0 = blockIdx.x*64, r0 = blockIdx.y*64;
  in  += (size_t)blockIdx.z * sIn;
  out += (size_t)blockIdx.z * sOut;
  const int tid = threadIdx.x;
  #pragma unroll
  for (int i=0;i<2;i++){
    int e = tid + i*256;
    int r = e >> 3, c8 = (e & 7) * 8;
    *(bf16x8*)&t[r][c8] = *(const bf16x8*)(in + (size_t)(r0+r)*ldin + c0 + c8);
  }
  __syncthreads();
  #pragma unroll
  for (int i=0;i<2;i++){
    int e = tid + i*256;
    int c = e >> 3, r8 = (e & 7) * 8;
    bf16x8 v;
    #pragma unroll
    for (int j=0;j<8;j++) v[j] = t[r8+j][c];
    *(bf16x8*)(out + (size_t)(c0+c)*CHUNK_LEN + r0 + r8) = v;
  }
}

// initial w1^T bf16 shadow: w1tb[z][h][o] = (bf16)w1[z][o][h]
__global__ __launch_bounds__(256) void tcw1_k(const float* __restrict__ w1,
    bft* __restrict__ w1tb)
{
  size_t idx = (size_t)blockIdx.x*256 + threadIdx.x;
  int z = (int)(idx >> 18);
  int h = (int)((idx >> 9) & 511);
  int o = (int)(idx & 511);
  w1tb[idx] = (bft)w1[(size_t)z*FD*FD + (size_t)o*FD + h];
}

// ---------------------------------------------------------------------------
// v^T for attention PV: vT[h][d][s] = v[s][h*128+d] (raw v region of qkv).
// ---------------------------------------------------------------------------
__global__ __launch_bounds__(256) void vt_k(const bf16* __restrict__ qkv,
    bft* __restrict__ vT)
{
  __shared__ __align__(16) bft t[64*QKP];   // [s][d]
  const int s0 = blockIdx.x * 64;
  const int h  = blockIdx.y;
  const int tid = threadIdx.x;
  #pragma unroll
  for (int i=0;i<4;i++){
    int e = tid + i*256;
    int rr = e >> 4, doff = (e & 15) * 8;
    *(bf16x8*)(t + rr*QKP + doff) =
        *(const bf16x8*)((const bft*)qkv + (size_t)(s0+rr)*QKV3 + 2*HID + h*HD + doff);
  }
  __syncthreads();
  #pragma unroll
  for (int it=0; it<4; it++){
    int d = (tid >> 3) + it*32;
    int so8 = (tid & 7) * 8;
    bf16x8 v;
    #pragma unroll
    for (int j=0;j<8;j++) v[j] = t[(so8+j)*QKP + d];
    *(bf16x8*)(vT + ((size_t)(h*HD + d))*S_LEN + s0 + so8) = v;
  }
}

// ---------------------------------------------------------------------------
// RoPE cos/sin tables
// ---------------------------------------------------------------------------
__global__ void rope_k(float* __restrict__ rc, float* __restrict__ rs){
  int pos = blockIdx.x, d = threadIdx.x;
  float inv = 1.f / powf(500000.0f, (float)d * (1.0f/64.0f));
  float ang = (float)pos * inv;
  rc[pos*64+d] = cosf(ang);
  rs[pos*64+d] = sinf(ang);
}

// ---------------------------------------------------------------------------
// per-token learning rates
// ---------------------------------------------------------------------------
__global__ __launch_bounds__(256) void lr_k(const float* __restrict__ hidden,
    const float* __restrict__ lr_w, const float* __restrict__ lr_b,
    float* __restrict__ lro)
{
  __shared__ float hrow[HID];
  __shared__ float red[4][12];
  int s = blockIdx.x, tid = threadIdx.x;
  for(int i=0;i<HID/256;i++) hrow[tid+256*i] = hidden[(size_t)s*HID + tid + 256*i];
  __syncthreads();
  float part[12];
  #pragma unroll
  for(int o=0;o<12;o++) part[o]=0.f;
  for(int i=0;i<HID/256;i++){
    int j = tid + 256*i;
    float h = hrow[j];
    #pragma unroll
    for(int o=0;o<12;o++) part[o] += h * lr_w[o*HID + j];
  }
  int lane = tid & 63, w = tid >> 6;
  #pragma unroll
  for(int o=0;o<12;o++){
    float v = wave_sum(part[o]);
    if(lane==0) red[w][o] = v;
  }
  __syncthreads();
  if(tid < 12){
    float v = red[0][tid]+red[1][tid]+red[2][tid]+red[3][tid] + lr_b[tid] + BASE_LR_INV;
    float sp = (v > 20.f) ? v : log1pf(expf(v));
    lro[s*12 + tid] = sp;
  }
}

// ---------------------------------------------------------------------------
// E2a: per-token rmsnorm(q), rmsnorm(k), in place in qkv (bf16).
// ---------------------------------------------------------------------------
__global__ __launch_bounds__(256) void e2a_k(
    bf16* __restrict__ qkv,
    const float* __restrict__ qnw, const float* __restrict__ knw)
{
  __shared__ float red[8];
  int s = blockIdx.x, tid = threadIdx.x;
  int lane = tid & 63, w = tid >> 6;
  float qv[8], kv[8];
  float sq = 0.f, sk = 0.f;
  size_t base = (size_t)s*QKV3;
  #pragma unroll
  for(int i=0;i<8;i++){
    int j = tid*8 + i;
    qv[i] = bf2f(qkv[base + j]);
    kv[i] = bf2f(qkv[base + HID + j]);
    sq += qv[i]*qv[i]; sk += kv[i]*kv[i];
  }
  sq = wave_sum(sq); sk = wave_sum(sk);
  if(lane==0){ red[w] = sq; red[4+w] = sk; }
  __syncthreads();
  float rq = rsqrtf((red[0]+red[1]+red[2]+red[3])*(1.f/HID) + 1e-6f);
  float rk = rsqrtf((red[4]+red[5]+red[6]+red[7])*(1.f/HID) + 1e-6f);
  #pragma unroll
  for(int i=0;i<8;i++){
    int j = tid*8 + i;
    qkv[base + j]       = f2bf(qv[i]*rq*qnw[j]);
    qkv[base + HID + j] = f2bf(kv[i]*rk*knw[j]);
  }
}

// ---------------------------------------------------------------------------
// E2b (after attention): overwrite q/k/v regions with fq/fk/fv.
// ---------------------------------------------------------------------------
__global__ __launch_bounds__(256) void e2b_k(
    bf16* __restrict__ qkv,
    const float* __restrict__ qks, const float* __restrict__ qko)
{
  int s = blockIdx.x, tid = threadIdx.x;
  size_t base = (size_t)s*QKV3;
  float a[8], b[8], vv[8];
  float ga = 0.f, gb2 = 0.f;
  #pragma unroll
  for(int i=0;i<8;i++){
    int j = tid*8 + i;
    float qn = bf2f(qkv[base + j]);
    float kn = bf2f(qkv[base + HID + j]);
    float v  = bf2f(qkv[base + 2*HID + j]);
    a[i] = siluf(qn*qks[2*j]   + qko[2*j]);
    b[i] = siluf(kn*qks[2*j+1] + qko[2*j+1]);
    vv[i] = siluf(v);
    ga += a[i]*a[i]; gb2 += b[i]*b[i];
  }
  ga = wave_sum(ga); gb2 = wave_sum(gb2);
  float iq = 1.f / fmaxf(sqrtf(ga), 1e-12f);
  float ik = 1.f / fmaxf(sqrtf(gb2), 1e-12f);
  #pragma unroll
  for(int i=0;i<8;i++){
    int j = tid*8 + i;
    qkv[base + j]         = f2bf(a[i]*iq);
    qkv[base + HID + j]   = f2bf(b[i]*ik);
    qkv[base + 2*HID + j] = f2bf(vv[i]);
  }
}

// ---------------------------------------------------------------------------
// MFMA sliding-window attention (window 256 incl self).
// ---------------------------------------------------------------------------
__global__ __launch_bounds__(256) void attn_k(
    const bf16* __restrict__ qkv, const bft* __restrict__ vT,
    const float* __restrict__ rc, const float* __restrict__ rs,
    float* __restrict__ attn)
{
  __shared__ __align__(16) bft Qs[64*QKP];
  __shared__ __align__(16) bft Ks[64*QKP];
  __shared__ __align__(16) bft Vs[128*VSP];
  __shared__ __align__(16) bft Ps[64*PSP];
  const int head = blockIdx.x >> 7;
  const int Q0 = (blockIdx.x & 127) * 64;
  const int tid = threadIdx.x;
  const int hb = head * HD;
  const int lane = tid & 63;
  const int wm = (tid >> 6) * 16;
  const int fr = lane & 15, fko = (lane >> 4) * 8;
  const int rbase = (lane >> 4) * 4;

  #pragma unroll
  for(int i=0;i<16;i++){
    int e = tid + i*256;
    int rr = e >> 6, d = e & 63;
    int qpos = Q0 + rr;
    size_t b = (size_t)qpos*QKV3 + hb;
    float x1 = bf2f(qkv[b + d]);
    float x2 = bf2f(qkv[b + d + 64]);
    float c = rc[qpos*64 + d], sn = rs[qpos*64 + d];
    Qs[rr*QKP + d]      = (bft)(x1*c - x2*sn);
    Qs[rr*QKP + d + 64] = (bft)(x2*c + x1*sn);
  }
  __syncthreads();
  bf16x8 qf[4];
  #pragma unroll
  for (int kk=0;kk<4;kk++)
    qf[kk] = *(const bf16x8*)(Qs + (wm+fr)*QKP + kk*32 + fko);

  f32x4 Ot[8];
  #pragma unroll
  for (int i=0;i<8;i++) Ot[i] = (f32x4){0.f,0.f,0.f,0.f};
  float m4[4], l4[4];
  #pragma unroll
  for (int r=0;r<4;r++){ m4[r] = -INFINITY; l4[r] = 0.f; }

  for (int kt=0; kt<5; kt++){
    const int kb = Q0 - 256 + kt*64;
    if (kb < 0) continue;
    __syncthreads();
    #pragma unroll
    for(int i=0;i<16;i++){
      int e = tid + i*256;
      int rr = e >> 6, d = e & 63;
      int kpos = kb + rr;
      size_t b = (size_t)kpos*QKV3 + HID + hb;
      float x1 = bf2f(qkv[b + d]);
      float x2 = bf2f(qkv[b + d + 64]);
      float c = rc[kpos*64 + d], sn = rs[kpos*64 + d];
      Ks[rr*QKP + d]      = (bft)(x1*c - x2*sn);
      Ks[rr*QKP + d + 64] = (bft)(x2*c + x1*sn);
    }
    {
      int d = tid >> 1, koff = (tid & 1) * 32;
      const bft* vrow = vT + ((size_t)(hb + d))*S_LEN + kb + koff;
      bft* lrow = Vs + d*VSP + koff;
      #pragma unroll
      for (int j8=0;j8<4;j8++)
        *(bf16x8*)(lrow + j8*8) = *(const bf16x8*)(vrow + j8*8);
    }
    __syncthreads();

    f32x4 st[4];
    #pragma unroll
    for (int nt=0;nt<4;nt++){
      f32x4 acc = (f32x4){0.f,0.f,0.f,0.f};
      #pragma unroll
      for (int kk=0;kk<4;kk++){
        bf16x8 kf = *(const bf16x8*)(Ks + (nt*16+fr)*QKP + kk*32 + fko);
        acc = __builtin_amdgcn_mfma_f32_16x16x32_bf16(qf[kk], kf, acc, 0, 0, 0);
      }
      st[nt] = acc;
    }

    float pv[4][4];
    #pragma unroll
    for (int r=0;r<4;r++){
      int qpos = Q0 + wm + rbase + r;
      float sm[4];
      float mx = -INFINITY;
      #pragma unroll
      for (int nt=0;nt<4;nt++){
        int kpos = kb + nt*16 + fr;
        bool valid = (kpos > qpos - 256) && (kpos <= qpos);
        float s = valid ? st[nt][r] * 0.088388347648318447f : -INFINITY;
        sm[nt] = s;
        mx = fmaxf(mx, s);
      }
      mx = fmaxf(mx, __shfl_xor(mx, 1, 64));
      mx = fmaxf(mx, __shfl_xor(mx, 2, 64));
      mx = fmaxf(mx, __shfl_xor(mx, 4, 64));
      mx = fmaxf(mx, __shfl_xor(mx, 8, 64));
      float mnew = fmaxf(m4[r], mx);
      float alpha = (mnew == -INFINITY) ? 1.f : __expf(m4[r] - mnew);
      float ps = 0.f;
      #pragma unroll
      for (int nt=0;nt<4;nt++){
        float p = (sm[nt] == -INFINITY) ? 0.f : __expf(sm[nt] - mnew);
        pv[nt][r] = p;
        ps += p;
      }
      ps += __shfl_xor(ps, 1, 64);
      ps += __shfl_xor(ps, 2, 64);
      ps += __shfl_xor(ps, 4, 64);
      ps += __shfl_xor(ps, 8, 64);
      l4[r] = l4[r]*alpha + ps;
      m4[r] = mnew;
      #pragma unroll
      for (int ct=0;ct<8;ct++) Ot[ct][r] *= alpha;
    }

    #pragma unroll
    for (int r=0;r<4;r++){
      int row = wm + rbase + r;
      #pragma unroll
      for (int nt=0;nt<4;nt++)
        Ps[row*PSP + nt*16 + fr] = (bft)pv[nt][r];
    }
    bf16x8 af[2];
    #pragma unroll
    for (int kk=0;kk<2;kk++){
      const bft* pp = Ps + (wm+fr)*PSP + kk*32 + fko;
      bf16x4 lo = *(const bf16x4*)pp;
      bf16x4 hi = *(const bf16x4*)(pp+4);
      bf16x8 a;
      #pragma unroll
      for (int j=0;j<4;j++){ a[j]=lo[j]; a[j+4]=hi[j]; }
      af[kk]=a;
    }
    #pragma unroll
    for (int ct=0;ct<8;ct++)
      #pragma unroll
      for (int kk=0;kk<2;kk++){
        bf16x8 bv = *(const bf16x8*)(Vs + (ct*16+fr)*VSP + kk*32 + fko);
        Ot[ct] = __builtin_amdgcn_mfma_f32_16x16x32_bf16(af[kk], bv, Ot[ct], 0, 0, 0);
      }
  }

  #pragma unroll
  for (int r=0;r<4;r++){
    float invl = 1.f / l4[r];
    int qpos = Q0 + wm + rbase + r;
    size_t ob = (size_t)qpos*HID + hb;
    #pragma unroll
    for (int ct=0;ct<8;ct++)
      attn[ob + ct*16 + fr] = Ot[ct][r] * invl;
  }
}

// ---------------------------------------------------------------------------
// TTT elementwise fwd: hid = silu(g)*hm ; opre = silu(qg)*qm (opre -> qg buf)
// ---------------------------------------------------------------------------
__global__ __launch_bounds__(256) void e3_k(
    const bf16* __restrict__ g, const bf16* __restrict__ hm,
    bf16* __restrict__ qg, const bf16* __restrict__ qm,
    bf16* __restrict__ hid)
{
  size_t idx = (size_t)blockIdx.x*256 + threadIdx.x;
  float opre = siluf(bf2f(qg[idx])) * bf2f(qm[idx]);
  hid[idx] = f2bf(siluf(bf2f(g[idx])) * bf2f(hm[idx]));
  qg[idx]  = f2bf(opre);
}

// ---------------------------------------------------------------------------
// TTT backprop elementwise (in place): a0->g, a2->hm, a1->dhid buffer.
// ---------------------------------------------------------------------------
__global__ __launch_bounds__(256) void e4_k(
    bf16* __restrict__ g, bf16* __restrict__ hm, bf16* __restrict__ dhid,
    const bf16* __restrict__ qkv, const float* __restrict__ lrb, int cbase)
{
  size_t idx = (size_t)blockIdx.x*256 + threadIdx.x;
  int h  = (int)(idx >> 20);
  int ci = (int)((idx >> 9) & 2047);
  int d  = (int)(idx & 511);
  int s  = cbase + ci;
  float l0  = lrb[s*12 + h];
  float l1  = lrb[s*12 + 4 + h];
  float l2v = lrb[s*12 + 8 + h];
  float gg = bf2f(g[idx]), hv = bf2f(hm[idx]), dh = bf2f(dhid[idx]);
  float sg = sigm(gg);
  float silu_g = gg * sg;
  float dhm = dh * silu_g;
  float dg  = dh * hv;
  float dgp = dg * (sg * (1.f + gg * (1.f - sg)));
  float fvv = bf2f(qkv[(size_t)s*QKV3 + 2*HID + h*FD + d]);
  g[idx]    = f2bf(dgp * l0);
  hm[idx]   = f2bf(dhm * l2v);
  dhid[idx] = f2bf(fvv * l1);
}

// ---------------------------------------------------------------------------
// E5 (per chunk): X = attn + rmsnorm(ofc)*ttt_norm_w -> q region of qkv
// ---------------------------------------------------------------------------
__global__ __launch_bounds__(256) void e5_k(const float* __restrict__ attn,
    const bf16* __restrict__ ofc, const float* __restrict__ tnw,
    bf16* __restrict__ qkv, int cbase)
{
  int ci = blockIdx.x, tid = threadIdx.x;
  int s = cbase + ci;
  int lane = tid & 63, w = tid >> 6;
  float o[8]; float ss = 0.f;
  size_t ob = ((size_t)w*CHUNK_LEN + ci)*FD + (size_t)lane*8;
  #pragma unroll
  for(int i=0;i<8;i++){ o[i] = bf2f(ofc[ob+i]); ss += o[i]*o[i]; }
  ss = wave_sum(ss);
  float inv = rsqrtf(ss*(1.f/FD) + 1e-6f);
  size_t xb = (size_t)s*QKV3 + w*FD + (size_t)lane*8;
  size_t ab = (size_t)s*HID  + w*FD + (size_t)lane*8;
  #pragma unroll
  for(int i=0;i<8;i++){
    int d = lane*8 + i;
    qkv[xb+i] = f2bf(attn[ab+i] + o[i]*inv*tnw[d]);
  }
}

// ---------------------------------------------------------------------------
extern "C" void kernel_launch(void* const* d_in, const int* in_sizes, int n_in,
                              void* d_out, int out_size, void* d_ws, size_t ws_size,
                              hipStream_t stream)
{
  (void)in_sizes; (void)n_in; (void)out_size;
  const float* hidden   = (const float*)d_in[0];
  const float* qkv_w    = (const float*)d_in[1];
  const float* q_norm_w = (const float*)d_in[2];
  const float* k_norm_w = (const float*)d_in[3];
  const float* qk_scale = (const float*)d_in[4];
  const float* qk_off   = (const float*)d_in[5];
  const float* lr_w     = (const float*)d_in[6];
  const float* lr_b     = (const float*)d_in[7];
  const float* w0_in    = (const float*)d_in[8];
  const float* w1_in    = (const float*)d_in[9];
  const float* w2_in    = (const float*)d_in[10];
  const float* ttt_nw   = (const float*)d_in[11];
  const float* o_proj   = (const float*)d_in[12];
  float* out = (float*)d_out;

  char* p = (char*)d_ws;
  auto alloc = [&](size_t n){ char* r = p; p += (n + 255) & ~(size_t)255; return (void*)r; };

  bf16*  qkv   = (bf16*) alloc((size_t)S_LEN*QKV3*sizeof(bf16));
  float* lrb   = (float*)alloc((size_t)S_LEN*12*sizeof(float));
  float* rc    = (float*)alloc((size_t)S_LEN*64*sizeof(float));
  float* rs    = (float*)alloc((size_t)S_LEN*64*sizeof(float));
  float* w0s   = (float*)alloc((size_t)NFW*FD*FD*sizeof(float));
  float* w1s   = (float*)alloc((size_t)NFW*FD*FD*sizeof(float));
  float* w2s   = (float*)alloc((size_t)NFW*FD*FD*sizeof(float));
  bft*   w1tb  = (bft*)  alloc((size_t)NFW*FD*FD*sizeof(bft));
  bf16*  gb    = (bf16*) alloc((size_t)NFW*CHUNK_LEN*FD*sizeof(bf16));
  bf16*  hmb   = (bf16*) alloc((size_t)NFW*CHUNK_LEN*FD*sizeof(bf16));
  bf16*  qgb   = (bf16*) alloc((size_t)NFW*CHUNK_LEN*FD*sizeof(bf16));
  bf16*  qmb   = (bf16*) alloc((size_t)NFW*CHUNK_LEN*FD*sizeof(bf16));
  bf16*  hidb  = (bf16*) alloc((size_t)NFW*CHUNK_LEN*FD*sizeof(bf16));
  bf16*  ofc   = (bf16*) alloc((size_t)NFW*CHUNK_LEN*FD*sizeof(bf16));
  bft*   fkT   = (bft*)  alloc((size_t)NFW*FD*CHUNK_LEN*sizeof(bft));
  bft*   hidT  = (bft*)  alloc((size_t)NFW*FD*CHUNK_LEN*sizeof(bft));
  bft*   a2T   = (bft*)  alloc((size_t)NFW*FD*CHUNK_LEN*sizeof(bft));
  bft*   a1T   = (bft*)  alloc((size_t)NFW*FD*CHUNK_LEN*sizeof(bft));

  if ((size_t)(p - (char*)d_ws) > ws_size) return;

  // Liveness aliases (no extra workspace):
  // hidden_bf (33.55 MB) = gb..qmb  — dead before chunk loop writes gb.
  // qkvw_bf   (25.17 MB) = fkT..a2T — dead before vt_k writes vT.
  // vT        (33.55 MB) = fkT..a1T — dead before chunk loop's tr_k.
  // opw_bf    ( 8.39 MB) = hidb..   — converted after last e5, before o_proj.
  bft* hidden_bf = (bft*)gb;
  bft* qkvw_bf   = (bft*)fkT;
  bft* vT        = (bft*)fkT;
  bft* opw_bf    = (bft*)hidb;

  float* attn = out;   // attn lives in d_out until the final projection

  hipMemcpyAsync(w0s, w0_in, (size_t)NFW*FD*FD*sizeof(float), hipMemcpyDeviceToDevice, stream);
  hipMemcpyAsync(w1s, w1_in, (size_t)NFW*FD*FD*sizeof(float), hipMemcpyDeviceToDevice, stream);
  hipMemcpyAsync(w2s, w2_in, (size_t)NFW*FD*FD*sizeof(float), hipMemcpyDeviceToDevice, stream);

  rope_k<<<S_LEN, 64, 0, stream>>>(rc, rs);
  lr_k<<<S_LEN, 256, 0, stream>>>(hidden, lr_w, lr_b, lrb);
  tcw1_k<<<NFW*FD*FD/256, 256, 0, stream>>>(w1_in, w1tb);
  cvt_k<<<(S_LEN*HID)/2048, 256, 0, stream>>>(hidden, hidden_bf);
  cvt_k<<<(QKV3*HID)/2048, 256, 0, stream>>>(qkv_w, qkvw_bf);

  // qkv = hidden @ qkv_w^T -> bf16   (all-bf16 async-staged)
  mgemm<128,128,0>(stream, hidden_bf, qkvw_bf, qkv, (bft*)nullptr,
      S_LEN, QKV3, HID, HID, HID, QKV3, 1, 0, 0, 0);

  e2a_k<<<S_LEN, 256, 0, stream>>>(qkv, q_norm_w, k_norm_w);
  vt_k<<<dim3(S_LEN/64, NH), 256, 0, stream>>>(qkv, vT);
  attn_k<<<NH*128, 256, 0, stream>>>(qkv, vT, rc, rs, attn);
  e2b_k<<<S_LEN, 256, 0, stream>>>(qkv, qk_scale, qk_off);

  const long sW  = (long)FD*FD;
  const long sCh = (long)CHUNK_LEN*FD;
  const long sT  = (long)FD*CHUNK_LEN;
  const int  NEL = NFW*CHUNK_LEN*FD/256;
  const dim3 tg(FD/64, CHUNK_LEN/64, NFW);

  for(int c=0; c<NCHUNK; c++){
    const bft* fqc = (const bft*)qkv + (size_t)c*CHUNK_LEN*QKV3;
    const bft* fkc = fqc + HID;
    const bft* fvc = fqc + 2*HID;
    mgemm<128,128,0>(stream, fkc, w0s, gb,  (bft*)nullptr, CHUNK_LEN, FD, FD, QKV3, FD, FD, NFW, FD, sW, sCh);
    mgemm<128,128,0>(stream, fkc, w2s, hmb, (bft*)nullptr, CHUNK_LEN, FD, FD, QKV3, FD, FD, NFW, FD, sW, sCh);
    mgemm<128,128,0>(stream, fqc, w0s, qgb, (bft*)nullptr, CHUNK_LEN, FD, FD, QKV3, FD, FD, NFW, FD, sW, sCh);
    mgemm<128,128,0>(stream, fqc, w2s, qmb, (bft*)nullptr, CHUNK_LEN, FD, FD, QKV3, FD, FD, NFW, FD, sW, sCh);
    e3_k<<<NEL, 256, 0, stream>>>(gb, hmb, qgb, qmb, hidb);
    mgemm<128,128,0>(stream, (const bft*)qgb, w1s, ofc, (bft*)nullptr, CHUNK_LEN, FD, FD, FD, FD, FD, NFW, sCh, sW, sCh);
    mgemm<128,128,0>(stream, fvc, (const bft*)w1tb, qmb, (bft*)nullptr, CHUNK_LEN, FD, FD, QKV3, FD, FD, NFW, FD, sW, sCh);
    e4_k<<<NEL, 256, 0, stream>>>(gb, hmb, qmb, qkv, lrb, c*CHUNK_LEN);
    tr_k<<<tg, 256, 0, stream>>>(fkc,              fkT,        QKV3, FD,  sT);
    tr_k<<<tg, 256, 0, stream>>>((const bft*)hidb, hidT,       FD,   sCh, sT);
    tr_k<<<tg, 256, 0, stream>>>((const bft*)gb,   (bft*)qgb,  FD,   sCh, sT);
    tr_k<<<tg, 256, 0, stream>>>((const bft*)hmb,  a2T,        FD,   sCh, sT);
    tr_k<<<tg, 256, 0, stream>>>((const bft*)qmb,  a1T,        FD,   sCh, sT);
    mgemm<64,64,2>(stream, (const bft*)qgb, fkT,  w0s, (bft*)nullptr, FD, FD, CHUNK_LEN, CHUNK_LEN, CHUNK_LEN, FD, NFW, sT, sT, sW);
    mgemm<64,64,2>(stream, a2T,             fkT,  w2s, (bft*)nullptr, FD, FD, CHUNK_LEN, CHUNK_LEN, CHUNK_LEN, FD, NFW, sT, sT, sW);
    mgemm<64,64,2>(stream, a1T,             hidT, w1s, w1tb,          FD, FD, CHUNK_LEN, CHUNK_LEN, CHUNK_LEN, FD, NFW, sT, sT, sW);
    e5_k<<<CHUNK_LEN, 256, 0, stream>>>(attn, ofc, ttt_nw, qkv, c*CHUNK_LEN);
  }

  // bf16 copy of o_proj (hidb/ofc are dead now), then final projection
  cvt_k<<<(HID*HID)/2048, 256, 0, stream>>>(o_proj, opw_bf);
  mgemm<128,128,1>(stream, (const bft*)qkv, opw_bf, out, (bft*)nullptr,
      S_LEN, HID, HID, QKV3, HID, HID, 1, 0, 0, 0);
}